// Round 1
// baseline (2048.094 us; speedup 1.0000x reference)
//
#include <hip/hip_runtime.h>

typedef __bf16 bf16;
typedef float f32x4 __attribute__((ext_vector_type(4)));
typedef __bf16 b8v __attribute__((ext_vector_type(8)));

#define S_LEN 2048
#define DMODEL 512
#define KDIM 128
#define NWIN 16
#define WIN 128

__device__ inline f32x4 mfma16(b8v a, b8v b, f32x4 c) {
  return __builtin_amdgcn_mfma_f32_16x16x32_bf16(a, b, c, 0, 0, 0);
}

// ---------------- conversion kernels ----------------

__global__ __launch_bounds__(256) void conv_kernel(const float* __restrict__ in, bf16* __restrict__ out, int n) {
  int i4 = (blockIdx.x * 256 + threadIdx.x) * 4;
  if (i4 < n) {
    float4 v = *(const float4*)(in + i4);
    out[i4]   = (bf16)v.x;
    out[i4+1] = (bf16)v.y;
    out[i4+2] = (bf16)v.z;
    out[i4+3] = (bf16)v.w;
  }
}

// W (Kd x N) f32 -> WT (N x Kd) bf16, batched over blockIdx.z
__global__ __launch_bounds__(256) void convT_kernel(const float* __restrict__ W, bf16* __restrict__ WT, int Kd, int N) {
  __shared__ float tile[32][33];
  int k0 = blockIdx.x * 32, n0 = blockIdx.y * 32;
  const float* Wl = W + (size_t)blockIdx.z * Kd * N;
  bf16* WTl = WT + (size_t)blockIdx.z * Kd * N;
  int tx = threadIdx.x & 31, ty = threadIdx.x >> 5;
  #pragma unroll
  for (int i = 0; i < 4; i++)
    tile[ty + i*8][tx] = Wl[(size_t)(k0 + ty + i*8) * N + n0 + tx];
  __syncthreads();
  #pragma unroll
  for (int i = 0; i < 4; i++)
    WTl[(size_t)(n0 + ty + i*8) * Kd + k0 + tx] = (bf16)tile[tx][ty + i*8];
}

// ---------------- time embedding MLP ----------------

__global__ __launch_bounds__(256) void time1_kernel(const int* __restrict__ t,
    const float* __restrict__ w1, const float* __restrict__ b1, float* __restrict__ te1) {
  __shared__ float te[512];
  int b = blockIdx.x >> 3;
  int c0 = (blockIdx.x & 7) * 256;
  int tid = threadIdx.x;
  float tt = (float)t[b] * 4.0f;
  {
    float fr = expf((float)tid * (-9.210340371976184f / 255.0f));
    float e = tt * fr;
    te[tid] = sinf(e);
    te[tid + 256] = cosf(e);
  }
  __syncthreads();
  int c = c0 + tid;
  float acc = b1[c];
  for (int dd = 0; dd < 512; dd++) acc = fmaf(te[dd], w1[(size_t)dd * 2048 + c], acc);
  float sp = (acc > 20.f) ? acc : log1pf(expf(acc));
  te1[b * 2048 + c] = acc * tanhf(sp);
}

__global__ __launch_bounds__(256) void time2_kernel(const float* __restrict__ te1,
    const float* __restrict__ w2, const float* __restrict__ b2, float* __restrict__ te2) {
  __shared__ float hb[2048];
  int b = blockIdx.x >> 1;
  int c0 = (blockIdx.x & 1) * 256;
  int tid = threadIdx.x;
  for (int i = tid; i < 2048; i += 256) hb[i] = te1[b * 2048 + i];
  __syncthreads();
  int c = c0 + tid;
  float acc = b2[c];
  for (int dd = 0; dd < 2048; dd++) acc = fmaf(hb[dd], w2[(size_t)dd * 512 + c], acc);
  te2[b * 512 + c] = acc;
}

// h[b][s][d] += ax1[s>>7][d] + ax2[s&127][d] + te2[b][d]
__global__ __launch_bounds__(256) void addpos_kernel(float* __restrict__ h,
    const float* __restrict__ ax1, const float* __restrict__ ax2, const float* __restrict__ te2) {
  size_t idx = (size_t)blockIdx.x * 256 + threadIdx.x;
  int d = (int)(idx & 511);
  size_t sd = idx >> 9;
  int s = (int)(sd & 2047);
  int b = (int)(sd >> 11);
  h[idx] += ax1[(s >> 7) * 512 + d] + ax2[(s & 127) * 512 + d] + te2[b * 512 + d];
}

// ---------------- layernorm: f32 in -> bf16 out ----------------

__global__ __launch_bounds__(256) void ln_kernel(const float* __restrict__ hsrc,
    const float* __restrict__ gg, const float* __restrict__ bb, bf16* __restrict__ out) {
  int row = blockIdx.x * 4 + (threadIdx.x >> 6);
  int lane = threadIdx.x & 63;
  const float* hr = hsrc + (size_t)row * 512 + lane * 8;
  float4 v0 = *(const float4*)hr;
  float4 v1 = *(const float4*)(hr + 4);
  float xv[8] = {v0.x, v0.y, v0.z, v0.w, v1.x, v1.y, v1.z, v1.w};
  float s = 0.f;
  #pragma unroll
  for (int j = 0; j < 8; j++) s += xv[j];
  #pragma unroll
  for (int off = 1; off < 64; off <<= 1) s += __shfl_xor(s, off);
  float mu = s * (1.f / 512.f);
  float vs = 0.f;
  #pragma unroll
  for (int j = 0; j < 8; j++) { float dd = xv[j] - mu; vs += dd * dd; }
  #pragma unroll
  for (int off = 1; off < 64; off <<= 1) vs += __shfl_xor(vs, off);
  float rstd = 1.f / sqrtf(vs * (1.f / 512.f) + 1e-5f);
  int dbase = lane * 8;
  bf16* orow = out + (size_t)row * 512 + dbase;
  #pragma unroll
  for (int j = 0; j < 8; j++)
    orow[j] = (bf16)((xv[j] - mu) * rstd * gg[dbase + j] + bb[dbase + j]);
}

// ---------------- generic MFMA GEMM ----------------
// C(MxN) = A(MxK,row-major,bf16) * BT(NxK,row-major,bf16)^T  with epilogues:
// EPI 0: Cb = acc (bf16, no bias)
// EPI 1: Cf = acc + bias
// EPI 2: Cf += acc + bias   (residual)
// EPI 3: Cb = gelu(acc + bias) (bf16)
// EPI 4: transposed output: Cf[b][col][s] = alpha*(acc + bias), row=b*2048+s
template<int EPI>
__global__ __launch_bounds__(256) void gemm_kernel(
    const bf16* __restrict__ A, const bf16* __restrict__ BT,
    const float* __restrict__ bias, float* __restrict__ Cf, bf16* __restrict__ Cb,
    int M, int N, int Kd, const float* __restrict__ alphap) {
  __shared__ bf16 As[128][56];
  __shared__ bf16 Bs[128][56];
  int tid = threadIdx.x;
  int lane = tid & 63, wid = tid >> 6;
  int g = lane >> 4, lr = lane & 15;
  int wm = wid >> 1, wn = wid & 1;
  int m0 = blockIdx.y * 128, n0 = blockIdx.x * 128;
  int srow = tid >> 1, skp = (tid & 1) * 16;
  f32x4 acc[4][4] = {};
  const bf16* pa = A + (size_t)(m0 + srow) * Kd + skp;
  const bf16* pb = BT + (size_t)(n0 + srow) * Kd + skp;
  for (int k0 = 0; k0 < Kd; k0 += 32) {
    b8v a0 = *(const b8v*)(pa);
    b8v a1 = *(const b8v*)(pa + 8);
    b8v b0 = *(const b8v*)(pb);
    b8v b1 = *(const b8v*)(pb + 8);
    *(b8v*)&As[srow][skp]     = a0;
    *(b8v*)&As[srow][skp + 8] = a1;
    *(b8v*)&Bs[srow][skp]     = b0;
    *(b8v*)&Bs[srow][skp + 8] = b1;
    pa += 32; pb += 32;
    __syncthreads();
    b8v af[4], bfv[4];
    #pragma unroll
    for (int i = 0; i < 4; i++) af[i]  = *(const b8v*)&As[wm * 64 + i * 16 + lr][g * 8];
    #pragma unroll
    for (int i = 0; i < 4; i++) bfv[i] = *(const b8v*)&Bs[wn * 64 + i * 16 + lr][g * 8];
    #pragma unroll
    for (int mf = 0; mf < 4; mf++)
      #pragma unroll
      for (int nf = 0; nf < 4; nf++)
        acc[mf][nf] = mfma16(af[mf], bfv[nf], acc[mf][nf]);
    __syncthreads();
  }
  float alp = (EPI == 4) ? alphap[0] : 1.0f;
  #pragma unroll
  for (int mf = 0; mf < 4; mf++) {
    #pragma unroll
    for (int nf = 0; nf < 4; nf++) {
      int col = n0 + wn * 64 + nf * 16 + lr;
      float bv = (EPI != 0) ? bias[col] : 0.0f;
      #pragma unroll
      for (int r = 0; r < 4; r++) {
        int row = m0 + wm * 64 + mf * 16 + g * 4 + r;
        float v = acc[mf][nf][r] + bv;
        if (EPI == 0) {
          Cb[(size_t)row * N + col] = (bf16)v;
        } else if (EPI == 1) {
          Cf[(size_t)row * N + col] = v;
        } else if (EPI == 2) {
          Cf[(size_t)row * N + col] += v;
        } else if (EPI == 3) {
          float ge = 0.5f * v * (1.0f + erff(v * 0.70710678118654752f));
          Cb[(size_t)row * N + col] = (bf16)ge;
        } else {
          int b_ = row >> 11, s_ = row & 2047;
          Cf[(size_t)b_ * (KDIM * S_LEN) + (size_t)col * S_LEN + s_] = alp * v;
        }
      }
    }
  }
}

// ---------------- local windowed attention (heads 0..3) ----------------
// grid (NWIN, B*4); flash over <=3 chunks of 128 keys
__global__ __launch_bounds__(256) void locattn_kernel(
    const bf16* __restrict__ qb, const bf16* __restrict__ kb, const bf16* __restrict__ vb,
    bf16* __restrict__ ab) {
  __shared__ bf16 Ks[128][72];        // [key][feat]
  __shared__ bf16 Vt[64][136];        // [feat][key]
  __shared__ bf16 Ps[4][32][136];     // per-wave P
  int w = blockIdx.x;
  int b = blockIdx.y >> 2, hh = blockIdx.y & 3;
  int tid = threadIdx.x, wid = tid >> 6, lane = tid & 63;
  int g = lane >> 4, lr = lane & 15;
  const size_t bsD = (size_t)b * S_LEN * DMODEL;
  int qrow0 = w * WIN + wid * 32;
  b8v qf[2][2];
  #pragma unroll
  for (int mf = 0; mf < 2; mf++)
    #pragma unroll
    for (int kf = 0; kf < 2; kf++)
      qf[mf][kf] = *(const b8v*)(qb + bsD + (size_t)(qrow0 + mf * 16 + lr) * DMODEL + hh * 64 + kf * 32 + g * 8);
  float mrun[2][4], lrun[2][4];
  f32x4 oacc[2][4] = {};
  #pragma unroll
  for (int mf = 0; mf < 2; mf++)
    #pragma unroll
    for (int r = 0; r < 4; r++) { mrun[mf][r] = -3e38f; lrun[mf][r] = 0.f; }
  for (int c = 0; c < 3; c++) {
    int wc = w - 1 + c;
    if (wc < 0 || wc >= NWIN) continue;   // whole-chunk mask (uniform)
    __syncthreads();
    {
      int row = tid >> 1, f0 = (tid & 1) * 32;
      const bf16* kp = kb + bsD + (size_t)(wc * WIN + row) * DMODEL + hh * 64 + f0;
      #pragma unroll
      for (int i = 0; i < 4; i++)
        *(b8v*)&Ks[row][f0 + i * 8] = *(const b8v*)(kp + i * 8);
      const bf16* vp = vb + bsD + (size_t)(wc * WIN + row) * DMODEL + hh * 64 + f0;
      #pragma unroll
      for (int i = 0; i < 4; i++) {
        b8v vv = *(const b8v*)(vp + i * 8);
        #pragma unroll
        for (int j = 0; j < 8; j++) Vt[f0 + i * 8 + j][row] = vv[j];
      }
    }
    __syncthreads();
    f32x4 sc[2][8] = {};
    #pragma unroll
    for (int nf = 0; nf < 8; nf++) {
      #pragma unroll
      for (int kf = 0; kf < 2; kf++) {
        b8v kfr = *(const b8v*)&Ks[nf * 16 + lr][kf * 32 + g * 8];
        sc[0][nf] = mfma16(qf[0][kf], kfr, sc[0][nf]);
        sc[1][nf] = mfma16(qf[1][kf], kfr, sc[1][nf]);
      }
    }
    #pragma unroll
    for (int mf = 0; mf < 2; mf++) {
      #pragma unroll
      for (int r = 0; r < 4; r++) {
        float cm = -3e38f;
        #pragma unroll
        for (int nf = 0; nf < 8; nf++) { sc[mf][nf][r] *= 0.125f; cm = fmaxf(cm, sc[mf][nf][r]); }
        cm = fmaxf(cm, __shfl_xor(cm, 1));
        cm = fmaxf(cm, __shfl_xor(cm, 2));
        cm = fmaxf(cm, __shfl_xor(cm, 4));
        cm = fmaxf(cm, __shfl_xor(cm, 8));
        float mnew = fmaxf(mrun[mf][r], cm);
        float corr = __expf(mrun[mf][r] - mnew);
        float rs = 0.f;
        #pragma unroll
        for (int nf = 0; nf < 8; nf++) { float p = __expf(sc[mf][nf][r] - mnew); sc[mf][nf][r] = p; rs += p; }
        rs += __shfl_xor(rs, 1); rs += __shfl_xor(rs, 2);
        rs += __shfl_xor(rs, 4); rs += __shfl_xor(rs, 8);
        lrun[mf][r] = lrun[mf][r] * corr + rs;
        mrun[mf][r] = mnew;
        #pragma unroll
        for (int vf = 0; vf < 4; vf++) oacc[mf][vf][r] *= corr;
      }
    }
    // P (bf16) -> LDS, per-wave
    #pragma unroll
    for (int mf = 0; mf < 2; mf++)
      #pragma unroll
      for (int nf = 0; nf < 8; nf++)
        #pragma unroll
        for (int r = 0; r < 4; r++)
          Ps[wid][mf * 16 + g * 4 + r][nf * 16 + lr] = (bf16)sc[mf][nf][r];
    // O += P * V
    #pragma unroll
    for (int kf2 = 0; kf2 < 4; kf2++) {
      b8v pa0 = *(const b8v*)&Ps[wid][lr][kf2 * 32 + g * 8];
      b8v pa1 = *(const b8v*)&Ps[wid][16 + lr][kf2 * 32 + g * 8];
      #pragma unroll
      for (int vf = 0; vf < 4; vf++) {
        b8v vv = *(const b8v*)&Vt[vf * 16 + lr][kf2 * 32 + g * 8];
        oacc[0][vf] = mfma16(pa0, vv, oacc[0][vf]);
        oacc[1][vf] = mfma16(pa1, vv, oacc[1][vf]);
      }
    }
  }
  #pragma unroll
  for (int mf = 0; mf < 2; mf++) {
    #pragma unroll
    for (int r = 0; r < 4; r++) {
      float inv = 1.0f / lrun[mf][r];
      int row = qrow0 + mf * 16 + g * 4 + r;
      #pragma unroll
      for (int vf = 0; vf < 4; vf++)
        ab[bsD + (size_t)row * DMODEL + hh * 64 + vf * 16 + lr] = (bf16)(oacc[mf][vf][r] * inv);
    }
  }
}

// ---------------- linear attention (heads 4..7) ----------------

__global__ __launch_bounds__(256) void la1_kernel(const bf16* __restrict__ kb,
    float* __restrict__ colmax, float* __restrict__ colsum) {
  int bh = blockIdx.x;
  int b = bh >> 2, hh = 4 + (bh & 3);
  int tid = threadIdx.x;
  int d = tid & 63, sg = tid >> 6;
  const float scale = 0.35355339059327373f;
  const bf16* base = kb + (size_t)b * S_LEN * DMODEL + hh * 64 + d;
  float mx = -3e38f;
  for (int s = sg; s < S_LEN; s += 4)
    mx = fmaxf(mx, (float)base[(size_t)s * DMODEL] * scale);
  __shared__ float red[4][64];
  red[sg][d] = mx;
  __syncthreads();
  mx = fmaxf(fmaxf(red[0][d], red[1][d]), fmaxf(red[2][d], red[3][d]));
  float sum = 0.f;
  for (int s = sg; s < S_LEN; s += 4)
    sum += __expf((float)base[(size_t)s * DMODEL] * scale - mx);
  __shared__ float red2[4][64];
  red2[sg][d] = sum;
  __syncthreads();
  if (sg == 0) {
    colmax[bh * 64 + d] = mx;
    colsum[bh * 64 + d] = red2[0][d] + red2[1][d] + red2[2][d] + red2[3][d];
  }
}

// partial ctx per s-chunk (deterministic, no atomics): part[ch][bh][d][e]
__global__ __launch_bounds__(256) void la2_kernel(const bf16* __restrict__ kb, const bf16* __restrict__ vb,
    const float* __restrict__ colmax, float* __restrict__ part) {
  int ch = blockIdx.x, bh = blockIdx.y;
  int b = bh >> 2, hh = 4 + (bh & 3);
  __shared__ float ke[128][65];
  __shared__ float vsh[128][65];
  int tid = threadIdx.x;
  const float scale = 0.35355339059327373f;
  const size_t base = (size_t)b * S_LEN * DMODEL + (size_t)ch * 128 * DMODEL + hh * 64;
  for (int i = tid; i < 128 * 64; i += 256) {
    int s = i >> 6, d = i & 63;
    float kv = (float)kb[base + (size_t)s * DMODEL + d] * scale;
    ke[s][d] = __expf(kv - colmax[bh * 64 + d]);
    vsh[s][d] = (float)vb[base + (size_t)s * DMODEL + d];
  }
  __syncthreads();
  int e = tid & 63, dg = tid >> 6;
  float accv[16] = {};
  for (int s = 0; s < 128; s++) {
    float vv = vsh[s][e];
    #pragma unroll
    for (int i = 0; i < 16; i++) accv[i] = fmaf(ke[s][dg * 16 + i], vv, accv[i]);
  }
  float* pp = part + ((size_t)ch * 32 + bh) * 4096 + (size_t)dg * 16 * 64 + e;
  #pragma unroll
  for (int i = 0; i < 16; i++) pp[i * 64] = accv[i];
}

__global__ __launch_bounds__(256) void la2b_kernel(const float* __restrict__ part,
    const float* __restrict__ colsum, float* __restrict__ ctx) {
  int idx = blockIdx.x * 256 + threadIdx.x;    // 131072 total
  int bh = idx >> 12;
  int d = (idx >> 6) & 63;
  float s = 0.f;
  for (int c = 0; c < 16; c++) s += part[(size_t)c * 131072 + idx];
  ctx[idx] = s / colsum[bh * 64 + d];
}

__global__ __launch_bounds__(256) void la3_kernel(const bf16* __restrict__ qb,
    const float* __restrict__ ctx, bf16* __restrict__ ab) {
  int ch = blockIdx.x, bh = blockIdx.y;
  int b = bh >> 2, hh = 4 + (bh & 3);
  __shared__ float cs[64][65];
  int tid = threadIdx.x;
  for (int i = tid; i < 4096; i += 256) cs[i >> 6][i & 63] = ctx[(size_t)bh * 4096 + i];
  __syncthreads();
  int s = ch * 128 + (tid >> 1);
  int e0 = (tid & 1) * 32;
  const float scale = 0.35355339059327373f;
  const bf16* qr = qb + (size_t)b * S_LEN * DMODEL + (size_t)s * DMODEL + hh * 64;
  float qv[64];
  float mx = -3e38f;
  #pragma unroll
  for (int i = 0; i < 8; i++) {
    b8v qq = *(const b8v*)(qr + i * 8);
    #pragma unroll
    for (int j = 0; j < 8; j++) { qv[i * 8 + j] = (float)qq[j] * scale; mx = fmaxf(mx, qv[i * 8 + j]); }
  }
  float sum = 0.f;
  #pragma unroll
  for (int d = 0; d < 64; d++) { qv[d] = __expf(qv[d] - mx); sum += qv[d]; }
  float inv = 1.f / sum;
  float o[32] = {};
  #pragma unroll
  for (int d = 0; d < 64; d++) {
    float qq = qv[d] * inv;
    #pragma unroll
    for (int j = 0; j < 32; j++) o[j] = fmaf(qq, cs[d][e0 + j], o[j]);
  }
  bf16* op = ab + (size_t)b * S_LEN * DMODEL + (size_t)s * DMODEL + hh * 64 + e0;
  #pragma unroll
  for (int j = 0; j < 32; j++) op[j] = (bf16)o[j];
}

// ---------------- launcher ----------------

extern "C" void kernel_launch(void* const* d_in, const int* in_sizes, int n_in,
                              void* d_out, int out_size, void* d_ws, size_t ws_size,
                              hipStream_t stream) {
  (void)in_sizes; (void)n_in; (void)out_size; (void)ws_size;
  const float* x_f     = (const float*)d_in[0];
  const int*   t_i     = (const int*)  d_in[1];
  const float* token_w = (const float*)d_in[2];
  const float* token_b = (const float*)d_in[3];
  const float* ax1     = (const float*)d_in[4];
  const float* ax2     = (const float*)d_in[5];
  const float* time_w1 = (const float*)d_in[6];
  const float* time_b1 = (const float*)d_in[7];
  const float* time_w2 = (const float*)d_in[8];
  const float* time_b2 = (const float*)d_in[9];
  const float* ln1_g   = (const float*)d_in[10];
  const float* ln1_b   = (const float*)d_in[11];
  const float* wq      = (const float*)d_in[12];
  const float* wk      = (const float*)d_in[13];
  const float* wv      = (const float*)d_in[14];
  const float* wo      = (const float*)d_in[15];
  const float* wo_b    = (const float*)d_in[16];
  const float* ln2_g   = (const float*)d_in[17];
  const float* ln2_b   = (const float*)d_in[18];
  const float* ff_w1   = (const float*)d_in[19];
  const float* ff_b1   = (const float*)d_in[20];
  const float* ff_w2   = (const float*)d_in[21];
  const float* ff_b2   = (const float*)d_in[22];
  const float* norm_g  = (const float*)d_in[23];
  const float* norm_b  = (const float*)d_in[24];
  const float* out_w   = (const float*)d_in[25];
  const float* out_b   = (const float*)d_in[26];
  const float* alpha   = (const float*)d_in[27];

  char* ws = (char*)d_ws;
  float* h      = (float*)(ws + 0);
  float* te1    = (float*)(ws + 33554432);
  float* te2    = (float*)(ws + 33619968);
  float* colmax = (float*)(ws + 33636352);
  float* colsum = (float*)(ws + 33644544);
  float* ctx    = (float*)(ws + 33652736);
  float* part   = (float*)(ws + 34177024);
  bf16* nbuf    = (bf16*)(ws + 42565632);
  bf16* qbuf    = (bf16*)(ws + 59342848);
  bf16* kbuf    = (bf16*)(ws + 76120064);
  bf16* vbuf    = (bf16*)(ws + 92897280);
  bf16* abuf    = (bf16*)(ws + 109674496);
  bf16* gbuf    = qbuf;  // ff1 output aliases q/k/v/a (dead by then), 67108864 B
  bf16* xw      = (bf16*)(ws + 126451712);
  bf16* token_wT= (bf16*)(ws + 130646016);
  bf16* wqT     = (bf16*)(ws + 130777088);
  bf16* wkT     = (bf16*)(ws + 132874240);
  bf16* wvT     = (bf16*)(ws + 134971392);
  bf16* woT     = (bf16*)(ws + 137068544);
  bf16* ff1T    = (bf16*)(ws + 139165696);
  bf16* ff2T    = (bf16*)(ws + 147554304);
  bf16* outwT   = (bf16*)(ws + 155942912);

  // weight/input conversions (transposed to N x K)
  conv_kernel<<<2048, 256, 0, stream>>>(x_f, xw, 2097152);
  convT_kernel<<<dim3(4, 16, 1),  256, 0, stream>>>(token_w, token_wT, 128, 512);
  convT_kernel<<<dim3(16, 16, 4), 256, 0, stream>>>(wq, wqT, 512, 512);
  convT_kernel<<<dim3(16, 16, 4), 256, 0, stream>>>(wk, wkT, 512, 512);
  convT_kernel<<<dim3(16, 16, 4), 256, 0, stream>>>(wv, wvT, 512, 512);
  convT_kernel<<<dim3(16, 16, 4), 256, 0, stream>>>(wo, woT, 512, 512);
  convT_kernel<<<dim3(16, 64, 4), 256, 0, stream>>>(ff_w1, ff1T, 512, 2048);
  convT_kernel<<<dim3(64, 16, 4), 256, 0, stream>>>(ff_w2, ff2T, 2048, 512);
  convT_kernel<<<dim3(16, 4, 1),  256, 0, stream>>>(out_w, outwT, 512, 128);

  // time embedding
  time1_kernel<<<64, 256, 0, stream>>>(t_i, time_w1, time_b1, te1);
  time2_kernel<<<16, 256, 0, stream>>>(te1, time_w2, time_b2, te2);

  // token embedding + positional/time add
  gemm_kernel<1><<<dim3(4, 128), 256, 0, stream>>>(xw, token_wT, token_b, h, nullptr, 16384, 512, 128, nullptr);
  addpos_kernel<<<32768, 256, 0, stream>>>(h, ax1, ax2, te2);

  for (int l = 0; l < 4; l++) {
    ln_kernel<<<4096, 256, 0, stream>>>(h, ln1_g + l * 512, ln1_b + l * 512, nbuf);
    gemm_kernel<0><<<dim3(4, 128), 256, 0, stream>>>(nbuf, wqT + (size_t)l * 262144, nullptr, nullptr, qbuf, 16384, 512, 512, nullptr);
    gemm_kernel<0><<<dim3(4, 128), 256, 0, stream>>>(nbuf, wkT + (size_t)l * 262144, nullptr, nullptr, kbuf, 16384, 512, 512, nullptr);
    gemm_kernel<0><<<dim3(4, 128), 256, 0, stream>>>(nbuf, wvT + (size_t)l * 262144, nullptr, nullptr, vbuf, 16384, 512, 512, nullptr);
    locattn_kernel<<<dim3(16, 32), 256, 0, stream>>>(qbuf, kbuf, vbuf, abuf);
    la1_kernel<<<32, 256, 0, stream>>>(kbuf, colmax, colsum);
    la2_kernel<<<dim3(16, 32), 256, 0, stream>>>(kbuf, vbuf, colmax, part);
    la2b_kernel<<<512, 256, 0, stream>>>(part, colsum, ctx);
    la3_kernel<<<dim3(16, 32), 256, 0, stream>>>(qbuf, ctx, abuf);
    gemm_kernel<2><<<dim3(4, 128), 256, 0, stream>>>(abuf, woT + (size_t)l * 262144, wo_b + l * 512, h, nullptr, 16384, 512, 512, nullptr);
    ln_kernel<<<4096, 256, 0, stream>>>(h, ln2_g + l * 512, ln2_b + l * 512, nbuf);
    gemm_kernel<3><<<dim3(16, 128), 256, 0, stream>>>(nbuf, ff1T + (size_t)l * 1048576, ff_b1 + l * 2048, nullptr, gbuf, 16384, 2048, 512, nullptr);
    gemm_kernel<2><<<dim3(4, 128), 256, 0, stream>>>(gbuf, ff2T + (size_t)l * 1048576, ff_b2 + l * 512, h, nullptr, 16384, 512, 2048, nullptr);
  }

  ln_kernel<<<4096, 256, 0, stream>>>(h, norm_g, norm_b, nbuf);
  gemm_kernel<4><<<dim3(1, 128), 256, 0, stream>>>(nbuf, outwT, out_b, (float*)d_out, nullptr, 16384, 128, 512, alpha);
}

// Round 2
// 1318.260 us; speedup vs baseline: 1.5536x; 1.5536x over previous
//
#include <hip/hip_runtime.h>

typedef __bf16 bf16;
typedef float f32x4 __attribute__((ext_vector_type(4)));
typedef __bf16 b8v __attribute__((ext_vector_type(8)));
typedef __bf16 b4v __attribute__((ext_vector_type(4)));

#define S_LEN 2048
#define DMODEL 512
#define KDIM 128
#define NWIN 16
#define WIN 128
#define QKVS 1536   // fused qkv row stride

__device__ inline f32x4 mfma16(b8v a, b8v b, f32x4 c) {
  return __builtin_amdgcn_mfma_f32_16x16x32_bf16(a, b, c, 0, 0, 0);
}

__device__ inline void gload16(const bf16* g, bf16* l) {
  __builtin_amdgcn_global_load_lds(
      (const __attribute__((address_space(1))) void*)g,
      (__attribute__((address_space(3))) void*)l, 16, 0, 0);
}

// ---------------- conversion kernels ----------------

__global__ __launch_bounds__(256) void conv_kernel(const float* __restrict__ in, bf16* __restrict__ out, int n) {
  int i4 = (blockIdx.x * 256 + threadIdx.x) * 4;
  if (i4 < n) {
    float4 v = *(const float4*)(in + i4);
    b4v o; o[0] = (bf16)v.x; o[1] = (bf16)v.y; o[2] = (bf16)v.z; o[3] = (bf16)v.w;
    *(b4v*)(out + i4) = o;
  }
}

// W (Kd x N) f32 -> WT (N x Kd) bf16; layer strides separate for fused qkv dest
__global__ __launch_bounds__(256) void convT_kernel(const float* __restrict__ W, bf16* __restrict__ WT,
                                                    int Kd, int N, size_t in_ls, size_t out_ls) {
  __shared__ float tile[32][33];
  int k0 = blockIdx.x * 32, n0 = blockIdx.y * 32;
  const float* Wl = W + (size_t)blockIdx.z * in_ls;
  bf16* WTl = WT + (size_t)blockIdx.z * out_ls;
  int tx = threadIdx.x & 31, ty = threadIdx.x >> 5;
  #pragma unroll
  for (int i = 0; i < 4; i++)
    tile[ty + i*8][tx] = Wl[(size_t)(k0 + ty + i*8) * N + n0 + tx];
  __syncthreads();
  #pragma unroll
  for (int i = 0; i < 4; i++)
    WTl[(size_t)(n0 + ty + i*8) * Kd + k0 + tx] = (bf16)tile[tx][ty + i*8];
}

// ---------------- time embedding MLP ----------------

// grid B*32; block computes 64 outputs; 4 waves split the 512-dd reduction
__global__ __launch_bounds__(256) void time1_kernel(const int* __restrict__ t,
    const float* __restrict__ w1, const float* __restrict__ b1, float* __restrict__ te1) {
  __shared__ float te[512];
  __shared__ float red[4][64];
  int b = blockIdx.x >> 5;
  int c0 = (blockIdx.x & 31) * 64;
  int tid = threadIdx.x;
  float tt = (float)t[b] * 4.0f;
  {
    float fr = expf((float)tid * (-9.210340371976184f / 255.0f));
    float e = tt * fr;
    te[tid] = sinf(e);
    te[tid + 256] = cosf(e);
  }
  __syncthreads();
  int lane = tid & 63, wv = tid >> 6;
  float acc = 0.f;
  const float* wcol = w1 + (size_t)(wv * 128) * 2048 + c0 + lane;
  for (int dd = 0; dd < 128; dd++) acc = fmaf(te[wv * 128 + dd], wcol[(size_t)dd * 2048], acc);
  red[wv][lane] = acc;
  __syncthreads();
  if (tid < 64) {
    float a = red[0][tid] + red[1][tid] + red[2][tid] + red[3][tid] + b1[c0 + tid];
    float sp = (a > 20.f) ? a : log1pf(expf(a));
    te1[b * 2048 + c0 + tid] = a * tanhf(sp);
  }
}

// grid B*8; block computes 64 outputs; 4 waves split the 2048-dd reduction
__global__ __launch_bounds__(256) void time2_kernel(const float* __restrict__ te1,
    const float* __restrict__ w2, const float* __restrict__ b2, float* __restrict__ te2) {
  __shared__ float hb[2048];
  __shared__ float red[4][64];
  int b = blockIdx.x >> 3;
  int c0 = (blockIdx.x & 7) * 64;
  int tid = threadIdx.x;
  for (int i = tid; i < 2048; i += 256) hb[i] = te1[b * 2048 + i];
  __syncthreads();
  int lane = tid & 63, wv = tid >> 6;
  float acc = 0.f;
  const float* wcol = w2 + (size_t)(wv * 512) * 512 + c0 + lane;
  for (int dd = 0; dd < 512; dd++) acc = fmaf(hb[wv * 512 + dd], wcol[(size_t)dd * 512], acc);
  red[wv][lane] = acc;
  __syncthreads();
  if (tid < 64)
    te2[b * 512 + c0 + tid] = red[0][tid] + red[1][tid] + red[2][tid] + red[3][tid] + b2[c0 + tid];
}

// h[b][s][d] += ax1[s>>7][d] + ax2[s&127][d] + te2[b][d]  (vectorized x4)
__global__ __launch_bounds__(256) void addpos_kernel(float* __restrict__ h,
    const float* __restrict__ ax1, const float* __restrict__ ax2, const float* __restrict__ te2) {
  size_t i4 = ((size_t)blockIdx.x * 256 + threadIdx.x) * 4;
  int d = (int)(i4 & 511);
  size_t sd = i4 >> 9;
  int s = (int)(sd & 2047);
  int b = (int)(sd >> 11);
  const float4 a1 = *(const float4*)(ax1 + (s >> 7) * 512 + d);
  const float4 a2 = *(const float4*)(ax2 + (s & 127) * 512 + d);
  const float4 tv = *(const float4*)(te2 + b * 512 + d);
  float4 v = *(const float4*)(h + i4);
  v.x += a1.x + a2.x + tv.x; v.y += a1.y + a2.y + tv.y;
  v.z += a1.z + a2.z + tv.z; v.w += a1.w + a2.w + tv.w;
  *(float4*)(h + i4) = v;
}

// ---------------- layernorm: f32 in -> bf16 out ----------------

__global__ __launch_bounds__(256) void ln_kernel(const float* __restrict__ hsrc,
    const float* __restrict__ gg, const float* __restrict__ bb, bf16* __restrict__ out) {
  int row = blockIdx.x * 4 + (threadIdx.x >> 6);
  int lane = threadIdx.x & 63;
  const float* hr = hsrc + (size_t)row * 512 + lane * 8;
  float4 v0 = *(const float4*)hr;
  float4 v1 = *(const float4*)(hr + 4);
  float xv[8] = {v0.x, v0.y, v0.z, v0.w, v1.x, v1.y, v1.z, v1.w};
  float s = 0.f;
  #pragma unroll
  for (int j = 0; j < 8; j++) s += xv[j];
  #pragma unroll
  for (int off = 1; off < 64; off <<= 1) s += __shfl_xor(s, off);
  float mu = s * (1.f / 512.f);
  float vs = 0.f;
  #pragma unroll
  for (int j = 0; j < 8; j++) { float dd = xv[j] - mu; vs += dd * dd; }
  #pragma unroll
  for (int off = 1; off < 64; off <<= 1) vs += __shfl_xor(vs, off);
  float rstd = 1.f / sqrtf(vs * (1.f / 512.f) + 1e-5f);
  int dbase = lane * 8;
  bf16* orow = out + (size_t)row * 512 + dbase;
  #pragma unroll
  for (int j = 0; j < 8; j++)
    orow[j] = (bf16)((xv[j] - mu) * rstd * gg[dbase + j] + bb[dbase + j]);
}

// ---------------- m97-style MFMA GEMM ----------------
// C(MxN) = A(MxK,bf16) * BT(NxK,bf16)^T ; 128x128 tile, BK=32, global_load_lds
// EPI 0: Cb = acc ; 1: Cf = acc+bias ; 2: Cf += acc+bias ; 3: Cb = gelu(acc+bias)
// EPI 4: d_out[b][col][s] = alpha*(acc+bias)  (transposed via LDS)
template<int EPI>
__global__ __launch_bounds__(256) void gemm_kernel(
    const bf16* __restrict__ A, const bf16* __restrict__ BT,
    const float* __restrict__ bias, float* __restrict__ Cf, bf16* __restrict__ Cb,
    int M, int N, int Kd, const float* __restrict__ alphap) {
  __shared__ bf16 As[128 * 32];
  __shared__ bf16 Bs[128 * 32];
  int tid = threadIdx.x;
  int lane = tid & 63, wid = tid >> 6;
  int g = lane >> 4, lr = lane & 15;
  int wm = wid >> 1, wn = wid & 1;
  int m0 = blockIdx.y * 128, n0 = blockIdx.x * 128;
  f32x4 acc[4][4] = {};
  int srow = wid * 16 + (lane >> 2);
  int scol = (lane & 3) * 8;
  const bf16* pa = A + (size_t)(m0 + srow) * Kd + scol;
  const bf16* pb = BT + (size_t)(n0 + srow) * Kd + scol;
  bf16* lA = As + wid * 16 * 32;
  bf16* lB = Bs + wid * 16 * 32;
  const size_t rstep = (size_t)64 * Kd;
  for (int k0 = 0; k0 < Kd; k0 += 32) {
    gload16(pa + k0, lA);
    gload16(pa + rstep + k0, lA + 64 * 32);
    gload16(pb + k0, lB);
    gload16(pb + rstep + k0, lB + 64 * 32);
    __syncthreads();
    b8v af[4], bfv[4];
    #pragma unroll
    for (int i = 0; i < 4; i++) af[i]  = *(const b8v*)&As[(wm * 64 + i * 16 + lr) * 32 + g * 8];
    #pragma unroll
    for (int i = 0; i < 4; i++) bfv[i] = *(const b8v*)&Bs[(wn * 64 + i * 16 + lr) * 32 + g * 8];
    #pragma unroll
    for (int mf = 0; mf < 4; mf++)
      #pragma unroll
      for (int nf = 0; nf < 4; nf++)
        acc[mf][nf] = mfma16(af[mf], bfv[nf], acc[mf][nf]);
    __syncthreads();
  }
  if constexpr (EPI == 4) {
    __shared__ float Ts[32][130];
    float alp = alphap[0];
    int b_ = m0 >> 11, sb = m0 & 2047;
    #pragma unroll
    for (int cg = 0; cg < 4; cg++) {
      __syncthreads();
      if (wn == (cg >> 1)) {
        #pragma unroll
        for (int nfi = 0; nfi < 2; nfi++) {
          int nf = (cg & 1) * 2 + nfi;
          int cl = nfi * 16 + lr;
          float bv = bias[cg * 32 + cl];
          #pragma unroll
          for (int mf = 0; mf < 4; mf++)
            #pragma unroll
            for (int r = 0; r < 4; r++)
              Ts[cl][wm * 64 + mf * 16 + g * 4 + r] = alp * (acc[mf][nf][r] + bv);
        }
      }
      __syncthreads();
      int cl = tid >> 3, soff = (tid & 7) * 16;
      int col = cg * 32 + cl;
      float* dst = Cf + (size_t)b_ * (KDIM * S_LEN) + (size_t)col * S_LEN + sb + soff;
      #pragma unroll
      for (int q4 = 0; q4 < 4; q4++) {
        float4 v = {Ts[cl][soff + q4*4], Ts[cl][soff + q4*4 + 1], Ts[cl][soff + q4*4 + 2], Ts[cl][soff + q4*4 + 3]};
        *(float4*)(dst + q4 * 4) = v;
      }
    }
    return;
  }
  #pragma unroll
  for (int mf = 0; mf < 4; mf++) {
    #pragma unroll
    for (int nf = 0; nf < 4; nf++) {
      int col = n0 + wn * 64 + nf * 16 + lr;
      float bv = (EPI != 0) ? bias[col] : 0.0f;
      #pragma unroll
      for (int r = 0; r < 4; r++) {
        int row = m0 + wm * 64 + mf * 16 + g * 4 + r;
        float v = acc[mf][nf][r] + bv;
        if (EPI == 0) {
          Cb[(size_t)row * N + col] = (bf16)v;
        } else if (EPI == 1) {
          Cf[(size_t)row * N + col] = v;
        } else if (EPI == 2) {
          Cf[(size_t)row * N + col] += v;
        } else if (EPI == 3) {
          float ge = 0.5f * v * (1.0f + erff(v * 0.70710678118654752f));
          Cb[(size_t)row * N + col] = (bf16)ge;
        }
      }
    }
  }
}

// ---------------- local windowed attention (heads 0..3) ----------------
// qkv fused layout: q at col 0, k at 512, v at 1024; row stride QKVS
__global__ __launch_bounds__(256) void locattn_kernel(
    const bf16* __restrict__ qkv, bf16* __restrict__ ab) {
  __shared__ bf16 Ks[128][72];        // [key][feat]
  __shared__ bf16 Vt[64][136];        // [feat][key]
  __shared__ bf16 Ps[4][32][136];     // per-wave P
  int w = blockIdx.x;
  int b = blockIdx.y >> 2, hh = blockIdx.y & 3;
  int tid = threadIdx.x, wid = tid >> 6, lane = tid & 63;
  int g = lane >> 4, lr = lane & 15;
  const size_t rowb = (size_t)b * S_LEN * QKVS;
  int qrow0 = w * WIN + wid * 32;
  b8v qf[2][2];
  #pragma unroll
  for (int mf = 0; mf < 2; mf++)
    #pragma unroll
    for (int kf = 0; kf < 2; kf++)
      qf[mf][kf] = *(const b8v*)(qkv + rowb + (size_t)(qrow0 + mf * 16 + lr) * QKVS + hh * 64 + kf * 32 + g * 8);
  float mrun[2][4], lrun[2][4];
  f32x4 oacc[2][4] = {};
  #pragma unroll
  for (int mf = 0; mf < 2; mf++)
    #pragma unroll
    for (int r = 0; r < 4; r++) { mrun[mf][r] = -3e38f; lrun[mf][r] = 0.f; }
  for (int c = 0; c < 3; c++) {
    int wc = w - 1 + c;
    if (wc < 0 || wc >= NWIN) continue;
    __syncthreads();
    {
      int row = tid >> 1, f0 = (tid & 1) * 32;
      const bf16* kp = qkv + rowb + (size_t)(wc * WIN + row) * QKVS + 512 + hh * 64 + f0;
      #pragma unroll
      for (int i = 0; i < 4; i++)
        *(b8v*)&Ks[row][f0 + i * 8] = *(const b8v*)(kp + i * 8);
      const bf16* vp = qkv + rowb + (size_t)(wc * WIN + row) * QKVS + 1024 + hh * 64 + f0;
      #pragma unroll
      for (int i = 0; i < 4; i++) {
        b8v vv = *(const b8v*)(vp + i * 8);
        #pragma unroll
        for (int j = 0; j < 8; j++) Vt[f0 + i * 8 + j][row] = vv[j];
      }
    }
    __syncthreads();
    f32x4 sc[2][8] = {};
    #pragma unroll
    for (int nf = 0; nf < 8; nf++) {
      #pragma unroll
      for (int kf = 0; kf < 2; kf++) {
        b8v kfr = *(const b8v*)&Ks[nf * 16 + lr][kf * 32 + g * 8];
        sc[0][nf] = mfma16(qf[0][kf], kfr, sc[0][nf]);
        sc[1][nf] = mfma16(qf[1][kf], kfr, sc[1][nf]);
      }
    }
    #pragma unroll
    for (int mf = 0; mf < 2; mf++) {
      #pragma unroll
      for (int r = 0; r < 4; r++) {
        float cm = -3e38f;
        #pragma unroll
        for (int nf = 0; nf < 8; nf++) { sc[mf][nf][r] *= 0.125f; cm = fmaxf(cm, sc[mf][nf][r]); }
        cm = fmaxf(cm, __shfl_xor(cm, 1));
        cm = fmaxf(cm, __shfl_xor(cm, 2));
        cm = fmaxf(cm, __shfl_xor(cm, 4));
        cm = fmaxf(cm, __shfl_xor(cm, 8));
        float mnew = fmaxf(mrun[mf][r], cm);
        float corr = __expf(mrun[mf][r] - mnew);
        float rs = 0.f;
        #pragma unroll
        for (int nf = 0; nf < 8; nf++) { float p = __expf(sc[mf][nf][r] - mnew); sc[mf][nf][r] = p; rs += p; }
        rs += __shfl_xor(rs, 1); rs += __shfl_xor(rs, 2);
        rs += __shfl_xor(rs, 4); rs += __shfl_xor(rs, 8);
        lrun[mf][r] = lrun[mf][r] * corr + rs;
        mrun[mf][r] = mnew;
        #pragma unroll
        for (int vf = 0; vf < 4; vf++) oacc[mf][vf][r] *= corr;
      }
    }
    #pragma unroll
    for (int mf = 0; mf < 2; mf++)
      #pragma unroll
      for (int nf = 0; nf < 8; nf++)
        #pragma unroll
        for (int r = 0; r < 4; r++)
          Ps[wid][mf * 16 + g * 4 + r][nf * 16 + lr] = (bf16)sc[mf][nf][r];
    #pragma unroll
    for (int kf2 = 0; kf2 < 4; kf2++) {
      b8v pa0 = *(const b8v*)&Ps[wid][lr][kf2 * 32 + g * 8];
      b8v pa1 = *(const b8v*)&Ps[wid][16 + lr][kf2 * 32 + g * 8];
      #pragma unroll
      for (int vf = 0; vf < 4; vf++) {
        b8v vv = *(const b8v*)&Vt[vf * 16 + lr][kf2 * 32 + g * 8];
        oacc[0][vf] = mfma16(pa0, vv, oacc[0][vf]);
        oacc[1][vf] = mfma16(pa1, vv, oacc[1][vf]);
      }
    }
  }
  #pragma unroll
  for (int mf = 0; mf < 2; mf++) {
    #pragma unroll
    for (int r = 0; r < 4; r++) {
      float inv = 1.0f / lrun[mf][r];
      int row = qrow0 + mf * 16 + g * 4 + r;
      #pragma unroll
      for (int vf = 0; vf < 4; vf++)
        ab[(size_t)b * S_LEN * DMODEL + (size_t)row * DMODEL + hh * 64 + vf * 16 + lr] = (bf16)(oacc[mf][vf][r] * inv);
    }
  }
}

// ---------------- linear attention (heads 4..7), no-max exp ----------------

// per chunk: partial ctx (64x64) + partial colsum; part[ch][bh][d][e], psum[ch][bh][d]
__global__ __launch_bounds__(256) void la2_kernel(const bf16* __restrict__ qkv,
    float* __restrict__ part, float* __restrict__ psum) {
  int ch = blockIdx.x, bh = blockIdx.y;
  int b = bh >> 2, hh = bh & 3;
  __shared__ float ke[128][65];
  __shared__ float vsh[128][65];
  __shared__ float red[4][64];
  int tid = threadIdx.x;
  const float scale = 0.35355339059327373f;
  const size_t base = ((size_t)b * S_LEN + (size_t)ch * 128) * QKVS;
  const bf16* kp = qkv + base + 768 + hh * 64;    // k block col 512 + head(4+hh)*64
  const bf16* vp = qkv + base + 1280 + hh * 64;   // v block col 1024 + head(4+hh)*64
  for (int i = tid; i < 1024; i += 256) {
    int s = i >> 3, d0 = (i & 7) * 8;
    b8v kv = *(const b8v*)(kp + (size_t)s * QKVS + d0);
    b8v vv = *(const b8v*)(vp + (size_t)s * QKVS + d0);
    #pragma unroll
    for (int j = 0; j < 8; j++) {
      ke[s][d0 + j] = __expf((float)kv[j] * scale);
      vsh[s][d0 + j] = (float)vv[j];
    }
  }
  __syncthreads();
  int d = tid & 63, sg = tid >> 6;
  float ps = 0.f;
  for (int s = sg * 32; s < sg * 32 + 32; s++) ps += ke[s][d];
  red[sg][d] = ps;
  int e = tid & 63, dg = tid >> 6;
  float accv[16] = {};
  for (int s = 0; s < 128; s++) {
    float vv2 = vsh[s][e];
    #pragma unroll
    for (int i = 0; i < 16; i++) accv[i] = fmaf(ke[s][dg * 16 + i], vv2, accv[i]);
  }
  __syncthreads();
  float* pp = part + ((size_t)ch * 32 + bh) * 4096 + (size_t)dg * 16 * 64 + e;
  #pragma unroll
  for (int i = 0; i < 16; i++) pp[i * 64] = accv[i];
  if (tid < 64)
    psum[((size_t)ch * 32 + bh) * 64 + tid] = red[0][tid] + red[1][tid] + red[2][tid] + red[3][tid];
}

__global__ __launch_bounds__(256) void la2b_kernel(const float* __restrict__ part,
    const float* __restrict__ psum, float* __restrict__ ctx) {
  int idx = blockIdx.x * 256 + threadIdx.x;    // 131072 total
  int bh = idx >> 12;
  int d = (idx >> 6) & 63;
  float s = 0.f, cs = 0.f;
  for (int c = 0; c < 16; c++) {
    s += part[(size_t)c * 131072 + idx];
    cs += psum[(size_t)(c * 32 + bh) * 64 + d];
  }
  ctx[idx] = s / cs;
}

__global__ __launch_bounds__(256) void la3_kernel(const bf16* __restrict__ qkv,
    const float* __restrict__ ctx, bf16* __restrict__ ab) {
  int ch = blockIdx.x, bh = blockIdx.y;
  int b = bh >> 2, hh = bh & 3;
  __shared__ float cs[64][65];
  int tid = threadIdx.x;
  for (int i = tid; i < 4096; i += 256) cs[i >> 6][i & 63] = ctx[(size_t)bh * 4096 + i];
  __syncthreads();
  int s = ch * 128 + (tid >> 1);
  int e0 = (tid & 1) * 32;
  const float scale = 0.35355339059327373f;
  const bf16* qr = qkv + ((size_t)b * S_LEN + s) * QKVS + 256 + hh * 64;  // q head 4+hh
  float qv[64];
  float mx = -3e38f;
  #pragma unroll
  for (int i = 0; i < 8; i++) {
    b8v qq = *(const b8v*)(qr + i * 8);
    #pragma unroll
    for (int j = 0; j < 8; j++) { qv[i * 8 + j] = (float)qq[j] * scale; mx = fmaxf(mx, qv[i * 8 + j]); }
  }
  float sum = 0.f;
  #pragma unroll
  for (int dd = 0; dd < 64; dd++) { qv[dd] = __expf(qv[dd] - mx); sum += qv[dd]; }
  float inv = 1.f / sum;
  float o[32] = {};
  #pragma unroll
  for (int dd = 0; dd < 64; dd++) {
    float qq = qv[dd] * inv;
    #pragma unroll
    for (int j = 0; j < 32; j++) o[j] = fmaf(qq, cs[dd][e0 + j], o[j]);
  }
  bf16* op = ab + ((size_t)b * S_LEN + s) * DMODEL + 256 + hh * 64 + e0;
  #pragma unroll
  for (int j = 0; j < 32; j++) op[j] = (bf16)o[j];
}

// ---------------- launcher ----------------

extern "C" void kernel_launch(void* const* d_in, const int* in_sizes, int n_in,
                              void* d_out, int out_size, void* d_ws, size_t ws_size,
                              hipStream_t stream) {
  (void)in_sizes; (void)n_in; (void)out_size; (void)ws_size;
  const float* x_f     = (const float*)d_in[0];
  const int*   t_i     = (const int*)  d_in[1];
  const float* token_w = (const float*)d_in[2];
  const float* token_b = (const float*)d_in[3];
  const float* ax1     = (const float*)d_in[4];
  const float* ax2     = (const float*)d_in[5];
  const float* time_w1 = (const float*)d_in[6];
  const float* time_b1 = (const float*)d_in[7];
  const float* time_w2 = (const float*)d_in[8];
  const float* time_b2 = (const float*)d_in[9];
  const float* ln1_g   = (const float*)d_in[10];
  const float* ln1_b   = (const float*)d_in[11];
  const float* wq      = (const float*)d_in[12];
  const float* wk      = (const float*)d_in[13];
  const float* wv      = (const float*)d_in[14];
  const float* wo      = (const float*)d_in[15];
  const float* wo_b    = (const float*)d_in[16];
  const float* ln2_g   = (const float*)d_in[17];
  const float* ln2_b   = (const float*)d_in[18];
  const float* ff_w1   = (const float*)d_in[19];
  const float* ff_b1   = (const float*)d_in[20];
  const float* ff_w2   = (const float*)d_in[21];
  const float* ff_b2   = (const float*)d_in[22];
  const float* norm_g  = (const float*)d_in[23];
  const float* norm_b  = (const float*)d_in[24];
  const float* out_w   = (const float*)d_in[25];
  const float* out_b   = (const float*)d_in[26];
  const float* alpha   = (const float*)d_in[27];

  char* ws = (char*)d_ws;
  float* h      = (float*)(ws + 0);            // 33,554,432
  float* te1    = (float*)(ws + 33554432);     // 65,536
  float* te2    = (float*)(ws + 33619968);     // 16,384
  float* psum   = (float*)(ws + 33636352);     // 131,072
  float* ctx    = (float*)(ws + 33767424);     // 524,288
  float* part   = (float*)(ws + 34291712);     // 8,388,608
  bf16* nbuf    = (bf16*)(ws + 42680320);      // 16,777,216
  bf16* qkvb    = (bf16*)(ws + 59457536);      // 50,331,648
  bf16* abuf    = (bf16*)(ws + 109789184);     // 16,777,216
  bf16* gbuf    = qkvb;                        // ff1 out: 67,108,864 spans qkv+abuf (both dead)
  bf16* xw      = (bf16*)(ws + 126566400);     // 4,194,304
  bf16* token_wT= (bf16*)(ws + 130760704);     // 131,072
  bf16* wqkvT   = (bf16*)(ws + 130891776);     // 6,291,456  [L][1536][512]
  bf16* woT     = (bf16*)(ws + 137183232);     // 2,097,152
  bf16* ff1T    = (bf16*)(ws + 139280384);     // 8,388,608
  bf16* ff2T    = (bf16*)(ws + 147668992);     // 8,388,608
  bf16* outwT   = (bf16*)(ws + 156057600);     // 131,072

  conv_kernel<<<2048, 256, 0, stream>>>(x_f, xw, 2097152);
  convT_kernel<<<dim3(4, 16, 1),  256, 0, stream>>>(token_w, token_wT, 128, 512, 65536, 65536);
  convT_kernel<<<dim3(16, 16, 4), 256, 0, stream>>>(wq, wqkvT,           512, 512, 262144, 786432);
  convT_kernel<<<dim3(16, 16, 4), 256, 0, stream>>>(wk, wqkvT + 262144,  512, 512, 262144, 786432);
  convT_kernel<<<dim3(16, 16, 4), 256, 0, stream>>>(wv, wqkvT + 524288,  512, 512, 262144, 786432);
  convT_kernel<<<dim3(16, 16, 4), 256, 0, stream>>>(wo, woT, 512, 512, 262144, 262144);
  convT_kernel<<<dim3(16, 64, 4), 256, 0, stream>>>(ff_w1, ff1T, 512, 2048, 1048576, 1048576);
  convT_kernel<<<dim3(64, 16, 4), 256, 0, stream>>>(ff_w2, ff2T, 2048, 512, 1048576, 1048576);
  convT_kernel<<<dim3(16, 4, 1),  256, 0, stream>>>(out_w, outwT, 512, 128, 65536, 65536);

  time1_kernel<<<256, 256, 0, stream>>>(t_i, time_w1, time_b1, te1);
  time2_kernel<<<64, 256, 0, stream>>>(te1, time_w2, time_b2, te2);

  gemm_kernel<1><<<dim3(4, 128), 256, 0, stream>>>(xw, token_wT, token_b, h, nullptr, 16384, 512, 128, nullptr);
  addpos_kernel<<<8192, 256, 0, stream>>>(h, ax1, ax2, te2);

  for (int l = 0; l < 4; l++) {
    ln_kernel<<<4096, 256, 0, stream>>>(h, ln1_g + l * 512, ln1_b + l * 512, nbuf);
    gemm_kernel<0><<<dim3(12, 128), 256, 0, stream>>>(nbuf, wqkvT + (size_t)l * 786432, nullptr, nullptr, qkvb, 16384, 1536, 512, nullptr);
    locattn_kernel<<<dim3(16, 32), 256, 0, stream>>>(qkvb, abuf);
    la2_kernel<<<dim3(16, 32), 256, 0, stream>>>(qkvb, part, psum);
    la2b_kernel<<<512, 256, 0, stream>>>(part, psum, ctx);
    la3_kernel<<<dim3(16, 32), 256, 0, stream>>>(qkvb, ctx, abuf);
    gemm_kernel<2><<<dim3(4, 128), 256, 0, stream>>>(abuf, woT + (size_t)l * 262144, wo_b + l * 512, h, nullptr, 16384, 512, 512, nullptr);
    ln_kernel<<<4096, 256, 0, stream>>>(h, ln2_g + l * 512, ln2_b + l * 512, nbuf);
    gemm_kernel<3><<<dim3(16, 128), 256, 0, stream>>>(nbuf, ff1T + (size_t)l * 1048576, ff_b1 + l * 2048, nullptr, gbuf, 16384, 2048, 512, nullptr);
    gemm_kernel<2><<<dim3(4, 128), 256, 0, stream>>>(gbuf, ff2T + (size_t)l * 1048576, ff_b2 + l * 512, h, nullptr, 16384, 512, 2048, nullptr);
  }

  ln_kernel<<<4096, 256, 0, stream>>>(h, norm_g, norm_b, nbuf);
  gemm_kernel<4><<<dim3(1, 128), 256, 0, stream>>>(nbuf, outwT, out_b, (float*)d_out, nullptr, 16384, 128, 512, alpha);
}

// Round 3
// 1212.491 us; speedup vs baseline: 1.6892x; 1.0872x over previous
//
#include <hip/hip_runtime.h>

typedef __bf16 bf16;
typedef float f32x4 __attribute__((ext_vector_type(4)));
typedef __bf16 b8v __attribute__((ext_vector_type(8)));
typedef __bf16 b4v __attribute__((ext_vector_type(4)));

#define S_LEN 2048
#define DMODEL 512
#define KDIM 128
#define NWIN 16
#define WIN 128
#define QKVS 1536   // fused qkv row stride

__device__ inline f32x4 mfma16(b8v a, b8v b, f32x4 c) {
  return __builtin_amdgcn_mfma_f32_16x16x32_bf16(a, b, c, 0, 0, 0);
}

__device__ inline void gload16(const bf16* g, bf16* l) {
  __builtin_amdgcn_global_load_lds(
      (const __attribute__((address_space(1))) void*)g,
      (__attribute__((address_space(3))) void*)l, 16, 0, 0);
}

// ---------------- conversion kernels ----------------

__global__ __launch_bounds__(256) void conv_kernel(const float* __restrict__ in, bf16* __restrict__ out, int n) {
  int i4 = (blockIdx.x * 256 + threadIdx.x) * 4;
  if (i4 < n) {
    float4 v = *(const float4*)(in + i4);
    b4v o; o[0] = (bf16)v.x; o[1] = (bf16)v.y; o[2] = (bf16)v.z; o[3] = (bf16)v.w;
    *(b4v*)(out + i4) = o;
  }
}

// W (Kd x N) f32 -> WT (N x Kd) bf16; layer strides separate for fused qkv dest
__global__ __launch_bounds__(256) void convT_kernel(const float* __restrict__ W, bf16* __restrict__ WT,
                                                    int Kd, int N, size_t in_ls, size_t out_ls) {
  __shared__ float tile[32][33];
  int k0 = blockIdx.x * 32, n0 = blockIdx.y * 32;
  const float* Wl = W + (size_t)blockIdx.z * in_ls;
  bf16* WTl = WT + (size_t)blockIdx.z * out_ls;
  int tx = threadIdx.x & 31, ty = threadIdx.x >> 5;
  #pragma unroll
  for (int i = 0; i < 4; i++)
    tile[ty + i*8][tx] = Wl[(size_t)(k0 + ty + i*8) * N + n0 + tx];
  __syncthreads();
  #pragma unroll
  for (int i = 0; i < 4; i++)
    WTl[(size_t)(n0 + ty + i*8) * Kd + k0 + tx] = (bf16)tile[tx][ty + i*8];
}

// ---------------- time embedding MLP ----------------

__global__ __launch_bounds__(256) void time1_kernel(const int* __restrict__ t,
    const float* __restrict__ w1, const float* __restrict__ b1, float* __restrict__ te1) {
  __shared__ float te[512];
  __shared__ float red[4][64];
  int b = blockIdx.x >> 5;
  int c0 = (blockIdx.x & 31) * 64;
  int tid = threadIdx.x;
  float tt = (float)t[b] * 4.0f;
  {
    float fr = expf((float)tid * (-9.210340371976184f / 255.0f));
    float e = tt * fr;
    te[tid] = sinf(e);
    te[tid + 256] = cosf(e);
  }
  __syncthreads();
  int lane = tid & 63, wv = tid >> 6;
  float acc = 0.f;
  const float* wcol = w1 + (size_t)(wv * 128) * 2048 + c0 + lane;
  for (int dd = 0; dd < 128; dd++) acc = fmaf(te[wv * 128 + dd], wcol[(size_t)dd * 2048], acc);
  red[wv][lane] = acc;
  __syncthreads();
  if (tid < 64) {
    float a = red[0][tid] + red[1][tid] + red[2][tid] + red[3][tid] + b1[c0 + tid];
    float sp = (a > 20.f) ? a : log1pf(expf(a));
    te1[b * 2048 + c0 + tid] = a * tanhf(sp);
  }
}

__global__ __launch_bounds__(256) void time2_kernel(const float* __restrict__ te1,
    const float* __restrict__ w2, const float* __restrict__ b2, float* __restrict__ te2) {
  __shared__ float hb[2048];
  __shared__ float red[4][64];
  int b = blockIdx.x >> 3;
  int c0 = (blockIdx.x & 7) * 64;
  int tid = threadIdx.x;
  for (int i = tid; i < 2048; i += 256) hb[i] = te1[b * 2048 + i];
  __syncthreads();
  int lane = tid & 63, wv = tid >> 6;
  float acc = 0.f;
  const float* wcol = w2 + (size_t)(wv * 512) * 512 + c0 + lane;
  for (int dd = 0; dd < 512; dd++) acc = fmaf(hb[wv * 512 + dd], wcol[(size_t)dd * 512], acc);
  red[wv][lane] = acc;
  __syncthreads();
  if (tid < 64)
    te2[b * 512 + c0 + tid] = red[0][tid] + red[1][tid] + red[2][tid] + red[3][tid] + b2[c0 + tid];
}

// ---------------- layernorm: f32 in -> bf16 out ----------------

__global__ __launch_bounds__(256) void ln_kernel(const float* __restrict__ hsrc,
    const float* __restrict__ gg, const float* __restrict__ bb, bf16* __restrict__ out) {
  int row = blockIdx.x * 4 + (threadIdx.x >> 6);
  int lane = threadIdx.x & 63;
  const float* hr = hsrc + (size_t)row * 512 + lane * 8;
  float4 v0 = *(const float4*)hr;
  float4 v1 = *(const float4*)(hr + 4);
  float xv[8] = {v0.x, v0.y, v0.z, v0.w, v1.x, v1.y, v1.z, v1.w};
  float s = 0.f;
  #pragma unroll
  for (int j = 0; j < 8; j++) s += xv[j];
  #pragma unroll
  for (int off = 1; off < 64; off <<= 1) s += __shfl_xor(s, off);
  float mu = s * (1.f / 512.f);
  float vs = 0.f;
  #pragma unroll
  for (int j = 0; j < 8; j++) { float dd = xv[j] - mu; vs += dd * dd; }
  #pragma unroll
  for (int off = 1; off < 64; off <<= 1) vs += __shfl_xor(vs, off);
  float rstd = 1.f / sqrtf(vs * (1.f / 512.f) + 1e-5f);
  int dbase = lane * 8;
  bf16* orow = out + (size_t)row * 512 + dbase;
  #pragma unroll
  for (int j = 0; j < 8; j++)
    orow[j] = (bf16)((xv[j] - mu) * rstd * gg[dbase + j] + bb[dbase + j]);
}

// ---------------- double-buffered MFMA GEMM, XCD-swizzled 1D grid ----------------
// C(MxN) = A(MxK,bf16) * BT(NxK,bf16)^T ; 128x128 tile, BK=32.
// EPI 0: Cb = acc ; 2: Cf += acc+bias ; 3: Cb = gelu(acc+bias)
// EPI 4: d_out[b][col][s] = alpha*(acc+bias)  (transposed via LDS)
// EPI 5: Cf = acc+bias + ax1 + ax2 + te2 (token embed + pos)
template<int EPI>
__global__ __launch_bounds__(256) void gemm_kernel(
    const bf16* __restrict__ A, const bf16* __restrict__ BT,
    const float* __restrict__ bias, float* __restrict__ Cf, bf16* __restrict__ Cb,
    int N, int Kd, int nbx,
    const float* __restrict__ q1, const float* __restrict__ q2, const float* __restrict__ q3,
    const float* __restrict__ alphap) {
  __shared__ bf16 As[2][4096];
  __shared__ bf16 Bs[2][4096];
  int tid = threadIdx.x;
  int lane = tid & 63, wid = tid >> 6;
  int g = lane >> 4, lr = lane & 15;
  int wm = wid >> 1, wn = wid & 1;
  // bijective XCD swizzle: each XCD owns a contiguous vid range (contiguous m)
  int p = blockIdx.x;
  int cpx = (int)gridDim.x >> 3;
  int vid = (p & 7) * cpx + (p >> 3);
  int m0 = (vid / nbx) * 128;
  int n0 = (vid % nbx) * 128;
  f32x4 acc[4][4] = {};
  int srow = wid * 16 + (lane >> 2);
  int scol = (lane & 3) * 8;
  const bf16* pa = A + (size_t)(m0 + srow) * Kd + scol;
  const bf16* pb = BT + (size_t)(n0 + srow) * Kd + scol;
  const size_t rstep = (size_t)64 * Kd;
  int nt = Kd >> 5;
  auto stage = [&](int buf, int k0) {
    bf16* lA = &As[buf][wid * 512];
    bf16* lB = &Bs[buf][wid * 512];
    gload16(pa + k0, lA);
    gload16(pa + rstep + k0, lA + 2048);
    gload16(pb + k0, lB);
    gload16(pb + rstep + k0, lB + 2048);
  };
  stage(0, 0);
  __syncthreads();
  int cur = 0;
  for (int t = 0; t < nt; ++t) {
    if (t + 1 < nt) stage(cur ^ 1, (t + 1) * 32);   // prefetch overlaps compute
    b8v af[4], bfv[4];
    #pragma unroll
    for (int i = 0; i < 4; i++) af[i]  = *(const b8v*)&As[cur][(wm * 64 + i * 16 + lr) * 32 + g * 8];
    #pragma unroll
    for (int i = 0; i < 4; i++) bfv[i] = *(const b8v*)&Bs[cur][(wn * 64 + i * 16 + lr) * 32 + g * 8];
    #pragma unroll
    for (int mf = 0; mf < 4; mf++)
      #pragma unroll
      for (int nf = 0; nf < 4; nf++)
        acc[mf][nf] = mfma16(af[mf], bfv[nf], acc[mf][nf]);
    __syncthreads();   // drains vmcnt(0): prefetched tile ready; old buf safe to overwrite
    cur ^= 1;
  }
  if constexpr (EPI == 4) {
    __shared__ float Ts[32][130];
    float alp = alphap[0];
    int b_ = m0 >> 11, sb = m0 & 2047;
    #pragma unroll
    for (int cg = 0; cg < 4; cg++) {
      __syncthreads();
      if (wn == (cg >> 1)) {
        #pragma unroll
        for (int nfi = 0; nfi < 2; nfi++) {
          int nf = (cg & 1) * 2 + nfi;
          int cl = nfi * 16 + lr;
          float bv = bias[cg * 32 + cl];
          #pragma unroll
          for (int mf = 0; mf < 4; mf++)
            #pragma unroll
            for (int r = 0; r < 4; r++)
              Ts[cl][wm * 64 + mf * 16 + g * 4 + r] = alp * (acc[mf][nf][r] + bv);
        }
      }
      __syncthreads();
      int cl = tid >> 3, soff = (tid & 7) * 16;
      int col = cg * 32 + cl;
      float* dst = Cf + (size_t)b_ * (KDIM * S_LEN) + (size_t)col * S_LEN + sb + soff;
      #pragma unroll
      for (int q4 = 0; q4 < 4; q4++) {
        float4 v = {Ts[cl][soff + q4*4], Ts[cl][soff + q4*4 + 1], Ts[cl][soff + q4*4 + 2], Ts[cl][soff + q4*4 + 3]};
        *(float4*)(dst + q4 * 4) = v;
      }
    }
    return;
  }
  #pragma unroll
  for (int mf = 0; mf < 4; mf++) {
    #pragma unroll
    for (int nf = 0; nf < 4; nf++) {
      int col = n0 + wn * 64 + nf * 16 + lr;
      float bv = (EPI != 0) ? bias[col] : 0.0f;
      #pragma unroll
      for (int r = 0; r < 4; r++) {
        int row = m0 + wm * 64 + mf * 16 + g * 4 + r;
        float v = acc[mf][nf][r] + bv;
        if (EPI == 0) {
          Cb[(size_t)row * N + col] = (bf16)v;
        } else if (EPI == 2) {
          Cf[(size_t)row * N + col] += v;
        } else if (EPI == 3) {
          float ge = 0.5f * v * (1.0f + erff(v * 0.70710678118654752f));
          Cb[(size_t)row * N + col] = (bf16)ge;
        } else if (EPI == 5) {
          int b_ = row >> 11, s_ = row & 2047;
          float pv = q1[(s_ >> 7) * 512 + col] + q2[(s_ & 127) * 512 + col] + q3[b_ * 512 + col];
          Cf[(size_t)row * N + col] = v + pv;
        }
      }
    }
  }
}

// ---------------- local windowed attention (heads 0..3) ----------------
__global__ __launch_bounds__(256) void locattn_kernel(
    const bf16* __restrict__ qkv, bf16* __restrict__ ab) {
  __shared__ bf16 Ks[128][72];        // [key][feat]
  __shared__ bf16 Vt[64][136];        // [feat][key]
  __shared__ bf16 Ps[4][32][136];     // per-wave P
  int w = blockIdx.x;
  int b = blockIdx.y >> 2, hh = blockIdx.y & 3;
  int tid = threadIdx.x, wid = tid >> 6, lane = tid & 63;
  int g = lane >> 4, lr = lane & 15;
  const size_t rowb = (size_t)b * S_LEN * QKVS;
  int qrow0 = w * WIN + wid * 32;
  b8v qf[2][2];
  #pragma unroll
  for (int mf = 0; mf < 2; mf++)
    #pragma unroll
    for (int kf = 0; kf < 2; kf++)
      qf[mf][kf] = *(const b8v*)(qkv + rowb + (size_t)(qrow0 + mf * 16 + lr) * QKVS + hh * 64 + kf * 32 + g * 8);
  float mrun[2][4], lrun[2][4];
  f32x4 oacc[2][4] = {};
  #pragma unroll
  for (int mf = 0; mf < 2; mf++)
    #pragma unroll
    for (int r = 0; r < 4; r++) { mrun[mf][r] = -3e38f; lrun[mf][r] = 0.f; }
  for (int c = 0; c < 3; c++) {
    int wc = w - 1 + c;
    if (wc < 0 || wc >= NWIN) continue;
    __syncthreads();
    {
      int row = tid >> 1, f0 = (tid & 1) * 32;
      const bf16* kp = qkv + rowb + (size_t)(wc * WIN + row) * QKVS + 512 + hh * 64 + f0;
      #pragma unroll
      for (int i = 0; i < 4; i++)
        *(b8v*)&Ks[row][f0 + i * 8] = *(const b8v*)(kp + i * 8);
      const bf16* vp = qkv + rowb + (size_t)(wc * WIN + row) * QKVS + 1024 + hh * 64 + f0;
      #pragma unroll
      for (int i = 0; i < 4; i++) {
        b8v vv = *(const b8v*)(vp + i * 8);
        #pragma unroll
        for (int j = 0; j < 8; j++) Vt[f0 + i * 8 + j][row] = vv[j];
      }
    }
    __syncthreads();
    f32x4 sc[2][8] = {};
    #pragma unroll
    for (int nf = 0; nf < 8; nf++) {
      #pragma unroll
      for (int kf = 0; kf < 2; kf++) {
        b8v kfr = *(const b8v*)&Ks[nf * 16 + lr][kf * 32 + g * 8];
        sc[0][nf] = mfma16(qf[0][kf], kfr, sc[0][nf]);
        sc[1][nf] = mfma16(qf[1][kf], kfr, sc[1][nf]);
      }
    }
    #pragma unroll
    for (int mf = 0; mf < 2; mf++) {
      #pragma unroll
      for (int r = 0; r < 4; r++) {
        float cm = -3e38f;
        #pragma unroll
        for (int nf = 0; nf < 8; nf++) { sc[mf][nf][r] *= 0.125f; cm = fmaxf(cm, sc[mf][nf][r]); }
        cm = fmaxf(cm, __shfl_xor(cm, 1));
        cm = fmaxf(cm, __shfl_xor(cm, 2));
        cm = fmaxf(cm, __shfl_xor(cm, 4));
        cm = fmaxf(cm, __shfl_xor(cm, 8));
        float mnew = fmaxf(mrun[mf][r], cm);
        float corr = __expf(mrun[mf][r] - mnew);
        float rs = 0.f;
        #pragma unroll
        for (int nf = 0; nf < 8; nf++) { float p = __expf(sc[mf][nf][r] - mnew); sc[mf][nf][r] = p; rs += p; }
        rs += __shfl_xor(rs, 1); rs += __shfl_xor(rs, 2);
        rs += __shfl_xor(rs, 4); rs += __shfl_xor(rs, 8);
        lrun[mf][r] = lrun[mf][r] * corr + rs;
        mrun[mf][r] = mnew;
        #pragma unroll
        for (int vf = 0; vf < 4; vf++) oacc[mf][vf][r] *= corr;
      }
    }
    #pragma unroll
    for (int mf = 0; mf < 2; mf++)
      #pragma unroll
      for (int nf = 0; nf < 8; nf++)
        #pragma unroll
        for (int r = 0; r < 4; r++)
          Ps[wid][mf * 16 + g * 4 + r][nf * 16 + lr] = (bf16)sc[mf][nf][r];
    #pragma unroll
    for (int kf2 = 0; kf2 < 4; kf2++) {
      b8v pa0 = *(const b8v*)&Ps[wid][lr][kf2 * 32 + g * 8];
      b8v pa1 = *(const b8v*)&Ps[wid][16 + lr][kf2 * 32 + g * 8];
      #pragma unroll
      for (int vf = 0; vf < 4; vf++) {
        b8v vv = *(const b8v*)&Vt[vf * 16 + lr][kf2 * 32 + g * 8];
        oacc[0][vf] = mfma16(pa0, vv, oacc[0][vf]);
        oacc[1][vf] = mfma16(pa1, vv, oacc[1][vf]);
      }
    }
  }
  #pragma unroll
  for (int mf = 0; mf < 2; mf++) {
    #pragma unroll
    for (int r = 0; r < 4; r++) {
      float inv = 1.0f / lrun[mf][r];
      int row = qrow0 + mf * 16 + g * 4 + r;
      #pragma unroll
      for (int vf = 0; vf < 4; vf++)
        ab[(size_t)b * S_LEN * DMODEL + (size_t)row * DMODEL + hh * 64 + vf * 16 + lr] = (bf16)(oacc[mf][vf][r] * inv);
    }
  }
}

// ---------------- linear attention (heads 4..7), no-max exp ----------------

__global__ __launch_bounds__(256) void la2_kernel(const bf16* __restrict__ qkv,
    float* __restrict__ part, float* __restrict__ psum) {
  int ch = blockIdx.x, bh = blockIdx.y;
  int b = bh >> 2, hh = bh & 3;
  __shared__ float ke[128][65];
  __shared__ float vsh[128][65];
  __shared__ float red[4][64];
  int tid = threadIdx.x;
  const float scale = 0.35355339059327373f;
  const size_t base = ((size_t)b * S_LEN + (size_t)ch * 128) * QKVS;
  const bf16* kp = qkv + base + 768 + hh * 64;
  const bf16* vp = qkv + base + 1280 + hh * 64;
  for (int i = tid; i < 1024; i += 256) {
    int s = i >> 3, d0 = (i & 7) * 8;
    b8v kv = *(const b8v*)(kp + (size_t)s * QKVS + d0);
    b8v vv = *(const b8v*)(vp + (size_t)s * QKVS + d0);
    #pragma unroll
    for (int j = 0; j < 8; j++) {
      ke[s][d0 + j] = __expf((float)kv[j] * scale);
      vsh[s][d0 + j] = (float)vv[j];
    }
  }
  __syncthreads();
  int d = tid & 63, sg = tid >> 6;
  float ps = 0.f;
  for (int s = sg * 32; s < sg * 32 + 32; s++) ps += ke[s][d];
  red[sg][d] = ps;
  int e = tid & 63, dg = tid >> 6;
  float accv[16] = {};
  for (int s = 0; s < 128; s++) {
    float vv2 = vsh[s][e];
    #pragma unroll
    for (int i = 0; i < 16; i++) accv[i] = fmaf(ke[s][dg * 16 + i], vv2, accv[i]);
  }
  __syncthreads();
  float* pp = part + ((size_t)ch * 32 + bh) * 4096 + (size_t)dg * 16 * 64 + e;
  #pragma unroll
  for (int i = 0; i < 16; i++) pp[i * 64] = accv[i];
  if (tid < 64)
    psum[((size_t)ch * 32 + bh) * 64 + tid] = red[0][tid] + red[1][tid] + red[2][tid] + red[3][tid];
}

__global__ __launch_bounds__(256) void la2b_kernel(const float* __restrict__ part,
    const float* __restrict__ psum, float* __restrict__ ctx) {
  int idx = blockIdx.x * 256 + threadIdx.x;    // 131072 total
  int bh = idx >> 12;
  int d = (idx >> 6) & 63;
  float s = 0.f, cs = 0.f;
  for (int c = 0; c < 16; c++) {
    s += part[(size_t)c * 131072 + idx];
    cs += psum[(size_t)(c * 32 + bh) * 64 + d];
  }
  ctx[idx] = s / cs;
}

__global__ __launch_bounds__(256) void la3_kernel(const bf16* __restrict__ qkv,
    const float* __restrict__ ctx, bf16* __restrict__ ab) {
  int ch = blockIdx.x, bh = blockIdx.y;
  int b = bh >> 2, hh = bh & 3;
  __shared__ float cs[64][65];
  int tid = threadIdx.x;
  for (int i = tid; i < 4096; i += 256) cs[i >> 6][i & 63] = ctx[(size_t)bh * 4096 + i];
  __syncthreads();
  int s = ch * 128 + (tid >> 1);
  int e0 = (tid & 1) * 32;
  const float scale = 0.35355339059327373f;
  const bf16* qr = qkv + ((size_t)b * S_LEN + s) * QKVS + 256 + hh * 64;
  float qv[64];
  float mx = -3e38f;
  #pragma unroll
  for (int i = 0; i < 8; i++) {
    b8v qq = *(const b8v*)(qr + i * 8);
    #pragma unroll
    for (int j = 0; j < 8; j++) { qv[i * 8 + j] = (float)qq[j] * scale; mx = fmaxf(mx, qv[i * 8 + j]); }
  }
  float sum = 0.f;
  #pragma unroll
  for (int dd = 0; dd < 64; dd++) { qv[dd] = __expf(qv[dd] - mx); sum += qv[dd]; }
  float inv = 1.f / sum;
  float o[32] = {};
  #pragma unroll
  for (int dd = 0; dd < 64; dd++) {
    float qq = qv[dd] * inv;
    #pragma unroll
    for (int j = 0; j < 32; j++) o[j] = fmaf(qq, cs[dd][e0 + j], o[j]);
  }
  bf16* op = ab + ((size_t)b * S_LEN + s) * DMODEL + 256 + hh * 64 + e0;
  #pragma unroll
  for (int j = 0; j < 32; j++) op[j] = (bf16)o[j];
}

// ---------------- launcher ----------------

extern "C" void kernel_launch(void* const* d_in, const int* in_sizes, int n_in,
                              void* d_out, int out_size, void* d_ws, size_t ws_size,
                              hipStream_t stream) {
  (void)in_sizes; (void)n_in; (void)out_size; (void)ws_size;
  const float* x_f     = (const float*)d_in[0];
  const int*   t_i     = (const int*)  d_in[1];
  const float* token_w = (const float*)d_in[2];
  const float* token_b = (const float*)d_in[3];
  const float* ax1     = (const float*)d_in[4];
  const float* ax2     = (const float*)d_in[5];
  const float* time_w1 = (const float*)d_in[6];
  const float* time_b1 = (const float*)d_in[7];
  const float* time_w2 = (const float*)d_in[8];
  const float* time_b2 = (const float*)d_in[9];
  const float* ln1_g   = (const float*)d_in[10];
  const float* ln1_b   = (const float*)d_in[11];
  const float* wq      = (const float*)d_in[12];
  const float* wk      = (const float*)d_in[13];
  const float* wv      = (const float*)d_in[14];
  const float* wo      = (const float*)d_in[15];
  const float* wo_b    = (const float*)d_in[16];
  const float* ln2_g   = (const float*)d_in[17];
  const float* ln2_b   = (const float*)d_in[18];
  const float* ff_w1   = (const float*)d_in[19];
  const float* ff_b1   = (const float*)d_in[20];
  const float* ff_w2   = (const float*)d_in[21];
  const float* ff_b2   = (const float*)d_in[22];
  const float* norm_g  = (const float*)d_in[23];
  const float* norm_b  = (const float*)d_in[24];
  const float* out_w   = (const float*)d_in[25];
  const float* out_b   = (const float*)d_in[26];
  const float* alpha   = (const float*)d_in[27];

  char* ws = (char*)d_ws;
  float* h      = (float*)(ws + 0);            // 33,554,432
  float* te1    = (float*)(ws + 33554432);     // 65,536
  float* te2    = (float*)(ws + 33619968);     // 16,384
  float* psum   = (float*)(ws + 33636352);     // 131,072
  float* ctx    = (float*)(ws + 33767424);     // 524,288
  float* part   = (float*)(ws + 34291712);     // 8,388,608
  bf16* nbuf    = (bf16*)(ws + 42680320);      // 16,777,216
  bf16* qkvb    = (bf16*)(ws + 59457536);      // 50,331,648
  bf16* abuf    = (bf16*)(ws + 109789184);     // 16,777,216
  bf16* gbuf    = qkvb;                        // ff1 out aliases qkv+abuf (dead by then)
  bf16* xw      = (bf16*)(ws + 126566400);     // 4,194,304
  bf16* token_wT= (bf16*)(ws + 130760704);     // 131,072
  bf16* wqkvT   = (bf16*)(ws + 130891776);     // 6,291,456  [L][1536][512]
  bf16* woT     = (bf16*)(ws + 137183232);     // 2,097,152
  bf16* ff1T    = (bf16*)(ws + 139280384);     // 8,388,608
  bf16* ff2T    = (bf16*)(ws + 147668992);     // 8,388,608
  bf16* outwT   = (bf16*)(ws + 156057600);     // 131,072

  conv_kernel<<<2048, 256, 0, stream>>>(x_f, xw, 2097152);
  convT_kernel<<<dim3(4, 16, 1),  256, 0, stream>>>(token_w, token_wT, 128, 512, 65536, 65536);
  convT_kernel<<<dim3(16, 16, 4), 256, 0, stream>>>(wq, wqkvT,           512, 512, 262144, 786432);
  convT_kernel<<<dim3(16, 16, 4), 256, 0, stream>>>(wk, wqkvT + 262144,  512, 512, 262144, 786432);
  convT_kernel<<<dim3(16, 16, 4), 256, 0, stream>>>(wv, wqkvT + 524288,  512, 512, 262144, 786432);
  convT_kernel<<<dim3(16, 16, 4), 256, 0, stream>>>(wo, woT, 512, 512, 262144, 262144);
  convT_kernel<<<dim3(16, 64, 4), 256, 0, stream>>>(ff_w1, ff1T, 512, 2048, 1048576, 1048576);
  convT_kernel<<<dim3(64, 16, 4), 256, 0, stream>>>(ff_w2, ff2T, 2048, 512, 1048576, 1048576);
  convT_kernel<<<dim3(16, 4, 1),  256, 0, stream>>>(out_w, outwT, 512, 128, 65536, 65536);

  time1_kernel<<<256, 256, 0, stream>>>(t_i, time_w1, time_b1, te1);
  time2_kernel<<<64, 256, 0, stream>>>(te1, time_w2, time_b2, te2);

  // token embedding + pos/time add fused
  gemm_kernel<5><<<512, 256, 0, stream>>>(xw, token_wT, token_b, h, nullptr, 512, 128, 4, ax1, ax2, te2, nullptr);

  for (int l = 0; l < 4; l++) {
    ln_kernel<<<4096, 256, 0, stream>>>(h, ln1_g + l * 512, ln1_b + l * 512, nbuf);
    gemm_kernel<0><<<1536, 256, 0, stream>>>(nbuf, wqkvT + (size_t)l * 786432, nullptr, nullptr, qkvb, 1536, 512, 12, nullptr, nullptr, nullptr, nullptr);
    locattn_kernel<<<dim3(16, 32), 256, 0, stream>>>(qkvb, abuf);
    la2_kernel<<<dim3(16, 32), 256, 0, stream>>>(qkvb, part, psum);
    la2b_kernel<<<512, 256, 0, stream>>>(part, psum, ctx);
    la3_kernel<<<dim3(16, 32), 256, 0, stream>>>(qkvb, ctx, abuf);
    gemm_kernel<2><<<512, 256, 0, stream>>>(abuf, woT + (size_t)l * 262144, wo_b + l * 512, h, nullptr, 512, 512, 4, nullptr, nullptr, nullptr, nullptr);
    ln_kernel<<<4096, 256, 0, stream>>>(h, ln2_g + l * 512, ln2_b + l * 512, nbuf);
    gemm_kernel<3><<<2048, 256, 0, stream>>>(nbuf, ff1T + (size_t)l * 1048576, ff_b1 + l * 2048, nullptr, gbuf, 2048, 512, 16, nullptr, nullptr, nullptr, nullptr);
    gemm_kernel<2><<<512, 256, 0, stream>>>(gbuf, ff2T + (size_t)l * 1048576, ff_b2 + l * 512, h, nullptr, 512, 2048, 4, nullptr, nullptr, nullptr, nullptr);
  }

  ln_kernel<<<4096, 256, 0, stream>>>(h, norm_g, norm_b, nbuf);
  gemm_kernel<4><<<128, 256, 0, stream>>>(nbuf, outwT, out_b, (float*)d_out, nullptr, 128, 512, 1, nullptr, nullptr, nullptr, alpha);
}

// Round 4
// 1109.244 us; speedup vs baseline: 1.8464x; 1.0931x over previous
//
#include <hip/hip_runtime.h>

typedef __bf16 bf16;
typedef float f32x4 __attribute__((ext_vector_type(4)));
typedef __bf16 b8v __attribute__((ext_vector_type(8)));
typedef __bf16 b4v __attribute__((ext_vector_type(4)));

#define S_LEN 2048
#define DMODEL 512
#define KDIM 128
#define NWIN 16
#define WIN 128
#define QKVS 1536   // fused qkv row stride

__device__ inline f32x4 mfma16(b8v a, b8v b, f32x4 c) {
  return __builtin_amdgcn_mfma_f32_16x16x32_bf16(a, b, c, 0, 0, 0);
}

__device__ inline void gload16(const bf16* g, bf16* l) {
  __builtin_amdgcn_global_load_lds(
      (const __attribute__((address_space(1))) void*)g,
      (__attribute__((address_space(3))) void*)l, 16, 0, 0);
}

template<int N>
__device__ inline void waitvm() { asm volatile("s_waitcnt vmcnt(%0)" :: "n"(N) : "memory"); }
__device__ inline void barrier_raw() { asm volatile("s_barrier" ::: "memory"); }

// ---------------- conversion kernels ----------------

__global__ __launch_bounds__(256) void conv_kernel(const float* __restrict__ in, bf16* __restrict__ out, int n) {
  int i4 = (blockIdx.x * 256 + threadIdx.x) * 4;
  if (i4 < n) {
    float4 v = *(const float4*)(in + i4);
    b4v o; o[0] = (bf16)v.x; o[1] = (bf16)v.y; o[2] = (bf16)v.z; o[3] = (bf16)v.w;
    *(b4v*)(out + i4) = o;
  }
}

// W (Kd x N) f32 -> WT (N x Kd) bf16; layer strides separate for fused qkv dest
__global__ __launch_bounds__(256) void convT_kernel(const float* __restrict__ W, bf16* __restrict__ WT,
                                                    int Kd, int N, size_t in_ls, size_t out_ls) {
  __shared__ float tile[32][33];
  int k0 = blockIdx.x * 32, n0 = blockIdx.y * 32;
  const float* Wl = W + (size_t)blockIdx.z * in_ls;
  bf16* WTl = WT + (size_t)blockIdx.z * out_ls;
  int tx = threadIdx.x & 31, ty = threadIdx.x >> 5;
  #pragma unroll
  for (int i = 0; i < 4; i++)
    tile[ty + i*8][tx] = Wl[(size_t)(k0 + ty + i*8) * N + n0 + tx];
  __syncthreads();
  #pragma unroll
  for (int i = 0; i < 4; i++)
    WTl[(size_t)(n0 + ty + i*8) * Kd + k0 + tx] = (bf16)tile[tx][ty + i*8];
}

// ---------------- time embedding MLP ----------------

__global__ __launch_bounds__(256) void time1_kernel(const int* __restrict__ t,
    const float* __restrict__ w1, const float* __restrict__ b1, float* __restrict__ te1) {
  __shared__ float te[512];
  __shared__ float red[4][64];
  int b = blockIdx.x >> 5;
  int c0 = (blockIdx.x & 31) * 64;
  int tid = threadIdx.x;
  float tt = (float)t[b] * 4.0f;
  {
    float fr = expf((float)tid * (-9.210340371976184f / 255.0f));
    float e = tt * fr;
    te[tid] = sinf(e);
    te[tid + 256] = cosf(e);
  }
  __syncthreads();
  int lane = tid & 63, wv = tid >> 6;
  float acc = 0.f;
  const float* wcol = w1 + (size_t)(wv * 128) * 2048 + c0 + lane;
  for (int dd = 0; dd < 128; dd++) acc = fmaf(te[wv * 128 + dd], wcol[(size_t)dd * 2048], acc);
  red[wv][lane] = acc;
  __syncthreads();
  if (tid < 64) {
    float a = red[0][tid] + red[1][tid] + red[2][tid] + red[3][tid] + b1[c0 + tid];
    float sp = (a > 20.f) ? a : log1pf(expf(a));
    te1[b * 2048 + c0 + tid] = a * tanhf(sp);
  }
}

__global__ __launch_bounds__(256) void time2_kernel(const float* __restrict__ te1,
    const float* __restrict__ w2, const float* __restrict__ b2, float* __restrict__ te2) {
  __shared__ float hb[2048];
  __shared__ float red[4][64];
  int b = blockIdx.x >> 3;
  int c0 = (blockIdx.x & 7) * 64;
  int tid = threadIdx.x;
  for (int i = tid; i < 2048; i += 256) hb[i] = te1[b * 2048 + i];
  __syncthreads();
  int lane = tid & 63, wv = tid >> 6;
  float acc = 0.f;
  const float* wcol = w2 + (size_t)(wv * 512) * 512 + c0 + lane;
  for (int dd = 0; dd < 512; dd++) acc = fmaf(hb[wv * 512 + dd], wcol[(size_t)dd * 512], acc);
  red[wv][lane] = acc;
  __syncthreads();
  if (tid < 64)
    te2[b * 512 + c0 + tid] = red[0][tid] + red[1][tid] + red[2][tid] + red[3][tid] + b2[c0 + tid];
}

// ---------------- layernorm: f32 in -> bf16 out ----------------

__global__ __launch_bounds__(256) void ln_kernel(const float* __restrict__ hsrc,
    const float* __restrict__ gg, const float* __restrict__ bb, bf16* __restrict__ out) {
  int row = blockIdx.x * 4 + (threadIdx.x >> 6);
  int lane = threadIdx.x & 63;
  const float* hr = hsrc + (size_t)row * 512 + lane * 8;
  float4 v0 = *(const float4*)hr;
  float4 v1 = *(const float4*)(hr + 4);
  float xv[8] = {v0.x, v0.y, v0.z, v0.w, v1.x, v1.y, v1.z, v1.w};
  float s = 0.f;
  #pragma unroll
  for (int j = 0; j < 8; j++) s += xv[j];
  #pragma unroll
  for (int off = 1; off < 64; off <<= 1) s += __shfl_xor(s, off);
  float mu = s * (1.f / 512.f);
  float vs = 0.f;
  #pragma unroll
  for (int j = 0; j < 8; j++) { float dd = xv[j] - mu; vs += dd * dd; }
  #pragma unroll
  for (int off = 1; off < 64; off <<= 1) vs += __shfl_xor(vs, off);
  float rstd = 1.f / sqrtf(vs * (1.f / 512.f) + 1e-5f);
  int dbase = lane * 8;
  bf16* orow = out + (size_t)row * 512 + dbase;
  #pragma unroll
  for (int j = 0; j < 8; j++)
    orow[j] = (bf16)((xv[j] - mu) * rstd * gg[dbase + j] + bb[dbase + j]);
}

// ---------------- pipelined MFMA GEMM (T3+T4: 3-buffer, counted vmcnt) ----------------
// C(MxN) = A(MxK,bf16) * BT(NxK,bf16)^T ; 512 threads, 8 waves (2M x 4N); BK=32.
// 3 LDS k-tile buffers, 2-tiles-ahead prefetch via global_load_lds; one raw s_barrier
// per K-step with s_waitcnt vmcnt(LPI) (never 0 in steady state).
// LDS layout: [row][32k] with 2-bit XOR swizzle on 16B slots: slot ^= (row>>1)&3,
// applied on the GLOBAL source (linear gload_lds dest) and on the ds_read address.
// EPI 0: Cb = acc ; 2: Cf += acc+bias ; 3: Cb = gelu(acc+bias)
template<int EPI, int BM, int BN>
__global__ __launch_bounds__(512, 2) void gemm2_kernel(
    const bf16* __restrict__ A, const bf16* __restrict__ BT,
    const float* __restrict__ bias, float* __restrict__ Cf, bf16* __restrict__ Cb,
    int N, int Kd, int nbx) {
  constexpr int LA = BM / 128;          // A gloads per thread per k-tile
  constexpr int LB = BN / 128;
  constexpr int LPI = LA + LB;          // loads in flight per staged tile
  constexpr int EA = BM * 32;           // elems per A region
  constexpr int EB = BN * 32;
  constexpr int ER = EA + EB;
  constexpr int MF = BM / 32;           // per-wave row frags (2 M-waves)
  constexpr int NF = BN / 64;           // per-wave col frags (4 N-waves)
  __shared__ bf16 lds[ER * 3];
  int tid = threadIdx.x;
  int lane = tid & 63, wid = tid >> 6;
  int g = lane >> 4, lr = lane & 15;
  int wm = wid >> 2, wn = wid & 3;
  int p = blockIdx.x;
  int cpx = (int)gridDim.x >> 3;        // grid % 8 == 0 always
  int vid = (p & 7) * cpx + (p >> 3);
  int m0 = (vid / nbx) * BM;
  int n0 = (vid % nbx) * BN;
  f32x4 acc[MF][NF] = {};
  int rl = tid >> 2;                               // 0..127 (row within 128-row round)
  int csw = ((tid & 3) ^ ((rl >> 1) & 3)) * 8;     // swizzled 16B slot -> elem offset
  const bf16* pa = A + (size_t)(m0 + rl) * Kd + csw;
  const bf16* pb = BT + (size_t)(n0 + rl) * Kd + csw;
  int NT = Kd >> 5;
  auto stage = [&](int t, int buf) {
    int k0 = t << 5;
    bf16* base = lds + buf * ER + (wid << 9);      // wave-uniform dest
    #pragma unroll
    for (int rr = 0; rr < LA; rr++)
      gload16(pa + (size_t)(rr * 128) * Kd + k0, base + rr * 4096);
    #pragma unroll
    for (int rr = 0; rr < LB; rr++)
      gload16(pb + (size_t)(rr * 128) * Kd + k0, base + EA + rr * 4096);
  };
  stage(0, 0);
  stage(1, 1);
  waitvm<LPI>();        // tile 0 complete (FIFO retire; tile1's LPI may be outstanding)
  barrier_raw();
  for (int t = 0; t < NT; ++t) {
    if (t + 2 < NT) stage(t + 2, (t + 2) % 3);     // overwrites buffer freed at end of t-1
    const bf16* ba = lds + (t % 3) * ER;
    const bf16* bb = ba + EA;
    b8v af[MF], bfr[NF];
    #pragma unroll
    for (int i = 0; i < MF; i++) {
      int ra = wm * (BM / 2) + i * 16 + lr;
      af[i] = *(const b8v*)(ba + ra * 32 + ((g * 8) ^ (((ra >> 1) & 3) << 3)));
    }
    #pragma unroll
    for (int j = 0; j < NF; j++) {
      int rb = wn * (BN / 4) + j * 16 + lr;
      bfr[j] = *(const b8v*)(bb + rb * 32 + ((g * 8) ^ (((rb >> 1) & 3) << 3)));
    }
    __builtin_amdgcn_s_setprio(1);
    #pragma unroll
    for (int i = 0; i < MF; i++)
      #pragma unroll
      for (int j = 0; j < NF; j++)
        acc[i][j] = mfma16(af[i], bfr[j], acc[i][j]);
    __builtin_amdgcn_s_setprio(0);
    if (t + 1 < NT) {
      if (t + 2 < NT) waitvm<LPI>();   // tile t+1 ready; only tile t+2's LPI outstanding
      else            waitvm<0>();     // tail: drain last tile
      barrier_raw();
    }
  }
  #pragma unroll
  for (int i = 0; i < MF; i++) {
    #pragma unroll
    for (int j = 0; j < NF; j++) {
      int col = n0 + wn * (BN / 4) + j * 16 + lr;
      float bv = (EPI != 0) ? bias[col] : 0.0f;
      #pragma unroll
      for (int r = 0; r < 4; r++) {
        int row = m0 + wm * (BM / 2) + i * 16 + g * 4 + r;
        float v = acc[i][j][r] + bv;
        if (EPI == 0) {
          Cb[(size_t)row * N + col] = (bf16)v;
        } else if (EPI == 2) {
          Cf[(size_t)row * N + col] += v;
        } else if (EPI == 3) {
          float ge = 0.5f * v * (1.0f + erff(v * 0.70710678118654752f));
          Cb[(size_t)row * N + col] = (bf16)ge;
        }
      }
    }
  }
}

// ---------------- small-GEMM kernel (token embed EPI5, output EPI4) ----------------
template<int EPI>
__global__ __launch_bounds__(256) void gemm_kernel(
    const bf16* __restrict__ A, const bf16* __restrict__ BT,
    const float* __restrict__ bias, float* __restrict__ Cf, bf16* __restrict__ Cb,
    int N, int Kd, int nbx,
    const float* __restrict__ q1, const float* __restrict__ q2, const float* __restrict__ q3,
    const float* __restrict__ alphap) {
  __shared__ bf16 As[2][4096];
  __shared__ bf16 Bs[2][4096];
  int tid = threadIdx.x;
  int lane = tid & 63, wid = tid >> 6;
  int g = lane >> 4, lr = lane & 15;
  int wm = wid >> 1, wn = wid & 1;
  int p = blockIdx.x;
  int cpx = (int)gridDim.x >> 3;
  int vid = (p & 7) * cpx + (p >> 3);
  int m0 = (vid / nbx) * 128;
  int n0 = (vid % nbx) * 128;
  f32x4 acc[4][4] = {};
  int srow = wid * 16 + (lane >> 2);
  int scol = (lane & 3) * 8;
  const bf16* pa = A + (size_t)(m0 + srow) * Kd + scol;
  const bf16* pb = BT + (size_t)(n0 + srow) * Kd + scol;
  const size_t rstep = (size_t)64 * Kd;
  int nt = Kd >> 5;
  auto stage = [&](int buf, int k0) {
    bf16* lA = &As[buf][wid * 512];
    bf16* lB = &Bs[buf][wid * 512];
    gload16(pa + k0, lA);
    gload16(pa + rstep + k0, lA + 2048);
    gload16(pb + k0, lB);
    gload16(pb + rstep + k0, lB + 2048);
  };
  stage(0, 0);
  __syncthreads();
  int cur = 0;
  for (int t = 0; t < nt; ++t) {
    if (t + 1 < nt) stage(cur ^ 1, (t + 1) * 32);
    b8v af[4], bfv[4];
    #pragma unroll
    for (int i = 0; i < 4; i++) af[i]  = *(const b8v*)&As[cur][(wm * 64 + i * 16 + lr) * 32 + g * 8];
    #pragma unroll
    for (int i = 0; i < 4; i++) bfv[i] = *(const b8v*)&Bs[cur][(wn * 64 + i * 16 + lr) * 32 + g * 8];
    #pragma unroll
    for (int mf = 0; mf < 4; mf++)
      #pragma unroll
      for (int nf = 0; nf < 4; nf++)
        acc[mf][nf] = mfma16(af[mf], bfv[nf], acc[mf][nf]);
    __syncthreads();
    cur ^= 1;
  }
  if constexpr (EPI == 4) {
    __shared__ float Ts[32][130];
    float alp = alphap[0];
    int b_ = m0 >> 11, sb = m0 & 2047;
    #pragma unroll
    for (int cg = 0; cg < 4; cg++) {
      __syncthreads();
      if (wn == (cg >> 1)) {
        #pragma unroll
        for (int nfi = 0; nfi < 2; nfi++) {
          int nf = (cg & 1) * 2 + nfi;
          int cl = nfi * 16 + lr;
          float bv = bias[cg * 32 + cl];
          #pragma unroll
          for (int mf = 0; mf < 4; mf++)
            #pragma unroll
            for (int r = 0; r < 4; r++)
              Ts[cl][wm * 64 + mf * 16 + g * 4 + r] = alp * (acc[mf][nf][r] + bv);
        }
      }
      __syncthreads();
      int cl = tid >> 3, soff = (tid & 7) * 16;
      int col = cg * 32 + cl;
      float* dst = Cf + (size_t)b_ * (KDIM * S_LEN) + (size_t)col * S_LEN + sb + soff;
      #pragma unroll
      for (int q4 = 0; q4 < 4; q4++) {
        float4 v = {Ts[cl][soff + q4*4], Ts[cl][soff + q4*4 + 1], Ts[cl][soff + q4*4 + 2], Ts[cl][soff + q4*4 + 3]};
        *(float4*)(dst + q4 * 4) = v;
      }
    }
    return;
  }
  #pragma unroll
  for (int mf = 0; mf < 4; mf++) {
    #pragma unroll
    for (int nf = 0; nf < 4; nf++) {
      int col = n0 + wn * 64 + nf * 16 + lr;
      float bv = bias[col];
      #pragma unroll
      for (int r = 0; r < 4; r++) {
        int row = m0 + wm * 64 + mf * 16 + g * 4 + r;
        float v = acc[mf][nf][r] + bv;
        if (EPI == 5) {
          int b_ = row >> 11, s_ = row & 2047;
          float pv = q1[(s_ >> 7) * 512 + col] + q2[(s_ & 127) * 512 + col] + q3[b_ * 512 + col];
          Cf[(size_t)row * N + col] = v + pv;
        }
      }
    }
  }
}

// ---------------- local windowed attention (heads 0..3) ----------------
__global__ __launch_bounds__(256) void locattn_kernel(
    const bf16* __restrict__ qkv, bf16* __restrict__ ab) {
  __shared__ bf16 Ks[128][72];        // [key][feat]
  __shared__ bf16 Vt[64][136];        // [feat][key]
  __shared__ bf16 Ps[4][32][136];     // per-wave P
  int w = blockIdx.x;
  int b = blockIdx.y >> 2, hh = blockIdx.y & 3;
  int tid = threadIdx.x, wid = tid >> 6, lane = tid & 63;
  int g = lane >> 4, lr = lane & 15;
  const size_t rowb = (size_t)b * S_LEN * QKVS;
  int qrow0 = w * WIN + wid * 32;
  b8v qf[2][2];
  #pragma unroll
  for (int mf = 0; mf < 2; mf++)
    #pragma unroll
    for (int kf = 0; kf < 2; kf++)
      qf[mf][kf] = *(const b8v*)(qkv + rowb + (size_t)(qrow0 + mf * 16 + lr) * QKVS + hh * 64 + kf * 32 + g * 8);
  float mrun[2][4], lrun[2][4];
  f32x4 oacc[2][4] = {};
  #pragma unroll
  for (int mf = 0; mf < 2; mf++)
    #pragma unroll
    for (int r = 0; r < 4; r++) { mrun[mf][r] = -3e38f; lrun[mf][r] = 0.f; }
  for (int c = 0; c < 3; c++) {
    int wc = w - 1 + c;
    if (wc < 0 || wc >= NWIN) continue;
    __syncthreads();
    {
      int row = tid >> 1, f0 = (tid & 1) * 32;
      const bf16* kp = qkv + rowb + (size_t)(wc * WIN + row) * QKVS + 512 + hh * 64 + f0;
      #pragma unroll
      for (int i = 0; i < 4; i++)
        *(b8v*)&Ks[row][f0 + i * 8] = *(const b8v*)(kp + i * 8);
      const bf16* vp = qkv + rowb + (size_t)(wc * WIN + row) * QKVS + 1024 + hh * 64 + f0;
      #pragma unroll
      for (int i = 0; i < 4; i++) {
        b8v vv = *(const b8v*)(vp + i * 8);
        #pragma unroll
        for (int j = 0; j < 8; j++) Vt[f0 + i * 8 + j][row] = vv[j];
      }
    }
    __syncthreads();
    f32x4 sc[2][8] = {};
    #pragma unroll
    for (int nf = 0; nf < 8; nf++) {
      #pragma unroll
      for (int kf = 0; kf < 2; kf++) {
        b8v kfr = *(const b8v*)&Ks[nf * 16 + lr][kf * 32 + g * 8];
        sc[0][nf] = mfma16(qf[0][kf], kfr, sc[0][nf]);
        sc[1][nf] = mfma16(qf[1][kf], kfr, sc[1][nf]);
      }
    }
    #pragma unroll
    for (int mf = 0; mf < 2; mf++) {
      #pragma unroll
      for (int r = 0; r < 4; r++) {
        float cm = -3e38f;
        #pragma unroll
        for (int nf = 0; nf < 8; nf++) { sc[mf][nf][r] *= 0.125f; cm = fmaxf(cm, sc[mf][nf][r]); }
        cm = fmaxf(cm, __shfl_xor(cm, 1));
        cm = fmaxf(cm, __shfl_xor(cm, 2));
        cm = fmaxf(cm, __shfl_xor(cm, 4));
        cm = fmaxf(cm, __shfl_xor(cm, 8));
        float mnew = fmaxf(mrun[mf][r], cm);
        float corr = __expf(mrun[mf][r] - mnew);
        float rs = 0.f;
        #pragma unroll
        for (int nf = 0; nf < 8; nf++) { float p = __expf(sc[mf][nf][r] - mnew); sc[mf][nf][r] = p; rs += p; }
        rs += __shfl_xor(rs, 1); rs += __shfl_xor(rs, 2);
        rs += __shfl_xor(rs, 4); rs += __shfl_xor(rs, 8);
        lrun[mf][r] = lrun[mf][r] * corr + rs;
        mrun[mf][r] = mnew;
        #pragma unroll
        for (int vf = 0; vf < 4; vf++) oacc[mf][vf][r] *= corr;
      }
    }
    #pragma unroll
    for (int mf = 0; mf < 2; mf++)
      #pragma unroll
      for (int nf = 0; nf < 8; nf++)
        #pragma unroll
        for (int r = 0; r < 4; r++)
          Ps[wid][mf * 16 + g * 4 + r][nf * 16 + lr] = (bf16)sc[mf][nf][r];
    #pragma unroll
    for (int kf2 = 0; kf2 < 4; kf2++) {
      b8v pa0 = *(const b8v*)&Ps[wid][lr][kf2 * 32 + g * 8];
      b8v pa1 = *(const b8v*)&Ps[wid][16 + lr][kf2 * 32 + g * 8];
      #pragma unroll
      for (int vf = 0; vf < 4; vf++) {
        b8v vv = *(const b8v*)&Vt[vf * 16 + lr][kf2 * 32 + g * 8];
        oacc[0][vf] = mfma16(pa0, vv, oacc[0][vf]);
        oacc[1][vf] = mfma16(pa1, vv, oacc[1][vf]);
      }
    }
  }
  #pragma unroll
  for (int mf = 0; mf < 2; mf++) {
    #pragma unroll
    for (int r = 0; r < 4; r++) {
      float inv = 1.0f / lrun[mf][r];
      int row = qrow0 + mf * 16 + g * 4 + r;
      #pragma unroll
      for (int vf = 0; vf < 4; vf++)
        ab[(size_t)b * S_LEN * DMODEL + (size_t)row * DMODEL + hh * 64 + vf * 16 + lr] = (bf16)(oacc[mf][vf][r] * inv);
    }
  }
}

// ---------------- linear attention (heads 4..7), no-max exp ----------------

__global__ __launch_bounds__(256) void la2_kernel(const bf16* __restrict__ qkv,
    float* __restrict__ part, float* __restrict__ psum) {
  int ch = blockIdx.x, bh = blockIdx.y;
  int b = bh >> 2, hh = bh & 3;
  __shared__ float ke[128][65];
  __shared__ float vsh[128][65];
  __shared__ float red[4][64];
  int tid = threadIdx.x;
  const float scale = 0.35355339059327373f;
  const size_t base = ((size_t)b * S_LEN + (size_t)ch * 128) * QKVS;
  const bf16* kp = qkv + base + 768 + hh * 64;
  const bf16* vp = qkv + base + 1280 + hh * 64;
  for (int i = tid; i < 1024; i += 256) {
    int s = i >> 3, d0 = (i & 7) * 8;
    b8v kv = *(const b8v*)(kp + (size_t)s * QKVS + d0);
    b8v vv = *(const b8v*)(vp + (size_t)s * QKVS + d0);
    #pragma unroll
    for (int j = 0; j < 8; j++) {
      ke[s][d0 + j] = __expf((float)kv[j] * scale);
      vsh[s][d0 + j] = (float)vv[j];
    }
  }
  __syncthreads();
  int d = tid & 63, sg = tid >> 6;
  float ps = 0.f;
  for (int s = sg * 32; s < sg * 32 + 32; s++) ps += ke[s][d];
  red[sg][d] = ps;
  int e = tid & 63, dg = tid >> 6;
  float accv[16] = {};
  for (int s = 0; s < 128; s++) {
    float vv2 = vsh[s][e];
    #pragma unroll
    for (int i = 0; i < 16; i++) accv[i] = fmaf(ke[s][dg * 16 + i], vv2, accv[i]);
  }
  __syncthreads();
  float* pp = part + ((size_t)ch * 32 + bh) * 4096 + (size_t)dg * 16 * 64 + e;
  #pragma unroll
  for (int i = 0; i < 16; i++) pp[i * 64] = accv[i];
  if (tid < 64)
    psum[((size_t)ch * 32 + bh) * 64 + tid] = red[0][tid] + red[1][tid] + red[2][tid] + red[3][tid];
}

__global__ __launch_bounds__(256) void la2b_kernel(const float* __restrict__ part,
    const float* __restrict__ psum, float* __restrict__ ctx) {
  int idx = blockIdx.x * 256 + threadIdx.x;    // 131072 total
  int bh = idx >> 12;
  int d = (idx >> 6) & 63;
  float s = 0.f, cs = 0.f;
  for (int c = 0; c < 16; c++) {
    s += part[(size_t)c * 131072 + idx];
    cs += psum[(size_t)(c * 32 + bh) * 64 + d];
  }
  ctx[idx] = s / cs;
}

__global__ __launch_bounds__(256) void la3_kernel(const bf16* __restrict__ qkv,
    const float* __restrict__ ctx, bf16* __restrict__ ab) {
  int ch = blockIdx.x, bh = blockIdx.y;
  int b = bh >> 2, hh = bh & 3;
  __shared__ float cs[64][65];
  int tid = threadIdx.x;
  for (int i = tid; i < 4096; i += 256) cs[i >> 6][i & 63] = ctx[(size_t)bh * 4096 + i];
  __syncthreads();
  int s = ch * 128 + (tid >> 1);
  int e0 = (tid & 1) * 32;
  const float scale = 0.35355339059327373f;
  const bf16* qr = qkv + ((size_t)b * S_LEN + s) * QKVS + 256 + hh * 64;
  float qv[64];
  float mx = -3e38f;
  #pragma unroll
  for (int i = 0; i < 8; i++) {
    b8v qq = *(const b8v*)(qr + i * 8);
    #pragma unroll
    for (int j = 0; j < 8; j++) { qv[i * 8 + j] = (float)qq[j] * scale; mx = fmaxf(mx, qv[i * 8 + j]); }
  }
  float sum = 0.f;
  #pragma unroll
  for (int dd = 0; dd < 64; dd++) { qv[dd] = __expf(qv[dd] - mx); sum += qv[dd]; }
  float inv = 1.f / sum;
  float o[32] = {};
  #pragma unroll
  for (int dd = 0; dd < 64; dd++) {
    float qq = qv[dd] * inv;
    #pragma unroll
    for (int j = 0; j < 32; j++) o[j] = fmaf(qq, cs[dd][e0 + j], o[j]);
  }
  bf16* op = ab + ((size_t)b * S_LEN + s) * DMODEL + 256 + hh * 64 + e0;
  #pragma unroll
  for (int j = 0; j < 32; j++) op[j] = (bf16)o[j];
}

// ---------------- launcher ----------------

extern "C" void kernel_launch(void* const* d_in, const int* in_sizes, int n_in,
                              void* d_out, int out_size, void* d_ws, size_t ws_size,
                              hipStream_t stream) {
  (void)in_sizes; (void)n_in; (void)out_size; (void)ws_size;
  const float* x_f     = (const float*)d_in[0];
  const int*   t_i     = (const int*)  d_in[1];
  const float* token_w = (const float*)d_in[2];
  const float* token_b = (const float*)d_in[3];
  const float* ax1     = (const float*)d_in[4];
  const float* ax2     = (const float*)d_in[5];
  const float* time_w1 = (const float*)d_in[6];
  const float* time_b1 = (const float*)d_in[7];
  const float* time_w2 = (const float*)d_in[8];
  const float* time_b2 = (const float*)d_in[9];
  const float* ln1_g   = (const float*)d_in[10];
  const float* ln1_b   = (const float*)d_in[11];
  const float* wq      = (const float*)d_in[12];
  const float* wk      = (const float*)d_in[13];
  const float* wv      = (const float*)d_in[14];
  const float* wo      = (const float*)d_in[15];
  const float* wo_b    = (const float*)d_in[16];
  const float* ln2_g   = (const float*)d_in[17];
  const float* ln2_b   = (const float*)d_in[18];
  const float* ff_w1   = (const float*)d_in[19];
  const float* ff_b1   = (const float*)d_in[20];
  const float* ff_w2   = (const float*)d_in[21];
  const float* ff_b2   = (const float*)d_in[22];
  const float* norm_g  = (const float*)d_in[23];
  const float* norm_b  = (const float*)d_in[24];
  const float* out_w   = (const float*)d_in[25];
  const float* out_b   = (const float*)d_in[26];
  const float* alpha   = (const float*)d_in[27];

  char* ws = (char*)d_ws;
  float* h      = (float*)(ws + 0);            // 33,554,432
  float* te1    = (float*)(ws + 33554432);     // 65,536
  float* te2    = (float*)(ws + 33619968);     // 16,384
  float* psum   = (float*)(ws + 33636352);     // 131,072
  float* ctx    = (float*)(ws + 33767424);     // 524,288
  float* part   = (float*)(ws + 34291712);     // 8,388,608
  bf16* nbuf    = (bf16*)(ws + 42680320);      // 16,777,216
  bf16* qkvb    = (bf16*)(ws + 59457536);      // 50,331,648
  bf16* abuf    = (bf16*)(ws + 109789184);     // 16,777,216
  bf16* gbuf    = qkvb;                        // ff1 out aliases qkv+abuf (dead by then)
  bf16* xw      = (bf16*)(ws + 126566400);     // 4,194,304
  bf16* token_wT= (bf16*)(ws + 130760704);     // 131,072
  bf16* wqkvT   = (bf16*)(ws + 130891776);     // 6,291,456  [L][1536][512]
  bf16* woT     = (bf16*)(ws + 137183232);     // 2,097,152
  bf16* ff1T    = (bf16*)(ws + 139280384);     // 8,388,608
  bf16* ff2T    = (bf16*)(ws + 147668992);     // 8,388,608
  bf16* outwT   = (bf16*)(ws + 156057600);     // 131,072

  conv_kernel<<<2048, 256, 0, stream>>>(x_f, xw, 2097152);
  convT_kernel<<<dim3(4, 16, 1),  256, 0, stream>>>(token_w, token_wT, 128, 512, 65536, 65536);
  convT_kernel<<<dim3(16, 16, 4), 256, 0, stream>>>(wq, wqkvT,           512, 512, 262144, 786432);
  convT_kernel<<<dim3(16, 16, 4), 256, 0, stream>>>(wk, wqkvT + 262144,  512, 512, 262144, 786432);
  convT_kernel<<<dim3(16, 16, 4), 256, 0, stream>>>(wv, wqkvT + 524288,  512, 512, 262144, 786432);
  convT_kernel<<<dim3(16, 16, 4), 256, 0, stream>>>(wo, woT, 512, 512, 262144, 262144);
  convT_kernel<<<dim3(16, 64, 4), 256, 0, stream>>>(ff_w1, ff1T, 512, 2048, 1048576, 1048576);
  convT_kernel<<<dim3(64, 16, 4), 256, 0, stream>>>(ff_w2, ff2T, 2048, 512, 1048576, 1048576);
  convT_kernel<<<dim3(16, 4, 1),  256, 0, stream>>>(out_w, outwT, 512, 128, 65536, 65536);

  time1_kernel<<<256, 256, 0, stream>>>(t_i, time_w1, time_b1, te1);
  time2_kernel<<<64, 256, 0, stream>>>(te1, time_w2, time_b2, te2);

  // token embedding + pos/time add fused
  gemm_kernel<5><<<512, 256, 0, stream>>>(xw, token_wT, token_b, h, nullptr, 512, 128, 4, ax1, ax2, te2, nullptr);

  for (int l = 0; l < 4; l++) {
    ln_kernel<<<4096, 256, 0, stream>>>(h, ln1_g + l * 512, ln1_b + l * 512, nbuf);
    gemm2_kernel<0, 128, 256><<<768, 512, 0, stream>>>(nbuf, wqkvT + (size_t)l * 786432, nullptr, nullptr, qkvb, 1536, 512, 6);
    locattn_kernel<<<dim3(16, 32), 256, 0, stream>>>(qkvb, abuf);
    la2_kernel<<<dim3(16, 32), 256, 0, stream>>>(qkvb, part, psum);
    la2b_kernel<<<512, 256, 0, stream>>>(part, psum, ctx);
    la3_kernel<<<dim3(16, 32), 256, 0, stream>>>(qkvb, ctx, abuf);
    gemm2_kernel<2, 128, 256><<<256, 512, 0, stream>>>(abuf, woT + (size_t)l * 262144, wo_b + l * 512, h, nullptr, 512, 512, 2);
    ln_kernel<<<4096, 256, 0, stream>>>(h, ln2_g + l * 512, ln2_b + l * 512, nbuf);
    gemm2_kernel<3, 256, 256><<<512, 512, 0, stream>>>(nbuf, ff1T + (size_t)l * 1048576, ff_b1 + l * 2048, nullptr, gbuf, 2048, 512, 8);
    gemm2_kernel<2, 128, 256><<<256, 512, 0, stream>>>(gbuf, ff2T + (size_t)l * 1048576, ff_b2 + l * 512, h, nullptr, 512, 2048, 2);
  }

  ln_kernel<<<4096, 256, 0, stream>>>(h, norm_g, norm_b, nbuf);
  gemm_kernel<4><<<128, 256, 0, stream>>>(nbuf, outwT, out_b, (float*)d_out, nullptr, 128, 512, 1, nullptr, nullptr, nullptr, alpha);
}

// Round 5
// 1092.196 us; speedup vs baseline: 1.8752x; 1.0156x over previous
//
#include <hip/hip_runtime.h>

typedef __bf16 bf16;
typedef float f32x4 __attribute__((ext_vector_type(4)));
typedef __bf16 b8v __attribute__((ext_vector_type(8)));
typedef __bf16 b4v __attribute__((ext_vector_type(4)));

#define S_LEN 2048
#define DMODEL 512
#define KDIM 128
#define NWIN 16
#define WIN 128
#define QKVS 1536   // fused qkv row stride

__device__ inline f32x4 mfma16(b8v a, b8v b, f32x4 c) {
  return __builtin_amdgcn_mfma_f32_16x16x32_bf16(a, b, c, 0, 0, 0);
}

__device__ inline void gload16(const bf16* g, bf16* l) {
  __builtin_amdgcn_global_load_lds(
      (const __attribute__((address_space(1))) void*)g,
      (__attribute__((address_space(3))) void*)l, 16, 0, 0);
}

template<int N>
__device__ inline void waitvm() { asm volatile("s_waitcnt vmcnt(%0)" :: "n"(N) : "memory"); }
template<int N>
__device__ inline void waitlgkm() { asm volatile("s_waitcnt lgkmcnt(%0)" :: "n"(N) : "memory"); }
__device__ inline void barrier_raw() { asm volatile("s_barrier" ::: "memory"); }

// ---------------- conversion kernels ----------------

__global__ __launch_bounds__(256) void conv_kernel(const float* __restrict__ in, bf16* __restrict__ out, int n) {
  int i4 = (blockIdx.x * 256 + threadIdx.x) * 4;
  if (i4 < n) {
    float4 v = *(const float4*)(in + i4);
    b4v o; o[0] = (bf16)v.x; o[1] = (bf16)v.y; o[2] = (bf16)v.z; o[3] = (bf16)v.w;
    *(b4v*)(out + i4) = o;
  }
}

// W (Kd x N) f32 -> WT (N x Kd) bf16; layer strides separate for fused qkv dest
__global__ __launch_bounds__(256) void convT_kernel(const float* __restrict__ W, bf16* __restrict__ WT,
                                                    int Kd, int N, size_t in_ls, size_t out_ls) {
  __shared__ float tile[32][33];
  int k0 = blockIdx.x * 32, n0 = blockIdx.y * 32;
  const float* Wl = W + (size_t)blockIdx.z * in_ls;
  bf16* WTl = WT + (size_t)blockIdx.z * out_ls;
  int tx = threadIdx.x & 31, ty = threadIdx.x >> 5;
  #pragma unroll
  for (int i = 0; i < 4; i++)
    tile[ty + i*8][tx] = Wl[(size_t)(k0 + ty + i*8) * N + n0 + tx];
  __syncthreads();
  #pragma unroll
  for (int i = 0; i < 4; i++)
    WTl[(size_t)(n0 + ty + i*8) * Kd + k0 + tx] = (bf16)tile[tx][ty + i*8];
}

// ---------------- time embedding MLP ----------------

__global__ __launch_bounds__(256) void time1_kernel(const int* __restrict__ t,
    const float* __restrict__ w1, const float* __restrict__ b1, float* __restrict__ te1) {
  __shared__ float te[512];
  __shared__ float red[4][64];
  int b = blockIdx.x >> 5;
  int c0 = (blockIdx.x & 31) * 64;
  int tid = threadIdx.x;
  float tt = (float)t[b] * 4.0f;
  {
    float fr = expf((float)tid * (-9.210340371976184f / 255.0f));
    float e = tt * fr;
    te[tid] = sinf(e);
    te[tid + 256] = cosf(e);
  }
  __syncthreads();
  int lane = tid & 63, wv = tid >> 6;
  float acc = 0.f;
  const float* wcol = w1 + (size_t)(wv * 128) * 2048 + c0 + lane;
  for (int dd = 0; dd < 128; dd++) acc = fmaf(te[wv * 128 + dd], wcol[(size_t)dd * 2048], acc);
  red[wv][lane] = acc;
  __syncthreads();
  if (tid < 64) {
    float a = red[0][tid] + red[1][tid] + red[2][tid] + red[3][tid] + b1[c0 + tid];
    float sp = (a > 20.f) ? a : log1pf(expf(a));
    te1[b * 2048 + c0 + tid] = a * tanhf(sp);
  }
}

__global__ __launch_bounds__(256) void time2_kernel(const float* __restrict__ te1,
    const float* __restrict__ w2, const float* __restrict__ b2, float* __restrict__ te2) {
  __shared__ float hb[2048];
  __shared__ float red[4][64];
  int b = blockIdx.x >> 3;
  int c0 = (blockIdx.x & 7) * 64;
  int tid = threadIdx.x;
  for (int i = tid; i < 2048; i += 256) hb[i] = te1[b * 2048 + i];
  __syncthreads();
  int lane = tid & 63, wv = tid >> 6;
  float acc = 0.f;
  const float* wcol = w2 + (size_t)(wv * 512) * 512 + c0 + lane;
  for (int dd = 0; dd < 512; dd++) acc = fmaf(hb[wv * 512 + dd], wcol[(size_t)dd * 512], acc);
  red[wv][lane] = acc;
  __syncthreads();
  if (tid < 64)
    te2[b * 512 + c0 + tid] = red[0][tid] + red[1][tid] + red[2][tid] + red[3][tid] + b2[c0 + tid];
}

// ---------------- layernorm: f32 in -> bf16 out ----------------

__global__ __launch_bounds__(256) void ln_kernel(const float* __restrict__ hsrc,
    const float* __restrict__ gg, const float* __restrict__ bb, bf16* __restrict__ out) {
  int row = blockIdx.x * 4 + (threadIdx.x >> 6);
  int lane = threadIdx.x & 63;
  const float* hr = hsrc + (size_t)row * 512 + lane * 8;
  float4 v0 = *(const float4*)hr;
  float4 v1 = *(const float4*)(hr + 4);
  float xv[8] = {v0.x, v0.y, v0.z, v0.w, v1.x, v1.y, v1.z, v1.w};
  float s = 0.f;
  #pragma unroll
  for (int j = 0; j < 8; j++) s += xv[j];
  #pragma unroll
  for (int off = 1; off < 64; off <<= 1) s += __shfl_xor(s, off);
  float mu = s * (1.f / 512.f);
  float vs = 0.f;
  #pragma unroll
  for (int j = 0; j < 8; j++) { float dd = xv[j] - mu; vs += dd * dd; }
  #pragma unroll
  for (int off = 1; off < 64; off <<= 1) vs += __shfl_xor(vs, off);
  float rstd = 1.f / sqrtf(vs * (1.f / 512.f) + 1e-5f);
  int dbase = lane * 8;
  bf16* orow = out + (size_t)row * 512 + dbase;
  #pragma unroll
  for (int j = 0; j < 8; j++)
    orow[j] = (bf16)((xv[j] - mu) * rstd * gg[dbase + j] + bb[dbase + j]);
}

// ---------------- phased MFMA GEMM (T3+T4+T5: NF phases, counted vmcnt/lgkmcnt) ----
// C(MxN) = A(MxK,bf16) * BT(NxK,bf16)^T ; 512 threads, 8 waves (2M x 4N); BK=32.
// 3 LDS k-tile buffers, 2-tiles-ahead prefetch; ONE vmcnt(LPI) + ONE s_barrier per
// K-tile (vmcnt(0) only at the last tile). Each K-tile runs NF phases: phase j
// prefetches B[j+1] via ds_read, waits lgkmcnt(counted), sched_barrier(0) fence
// (rule #18), then setprio(1)-wrapped MFMA cluster on column-frag j.
// LDS XOR swizzle on 16B slots: slot ^= (row>>1)&3, applied on the GLOBAL source
// (linear gload_lds dest) and on the ds_read address (both-sides rule #21).
// EPI 0: Cb = acc ; 2: Cf += acc+bias ; 3: Cb = gelu_tanh(acc+bias)
template<int EPI, int BM, int BN>
__global__ __launch_bounds__(512, 2) void gemm3_kernel(
    const bf16* __restrict__ A, const bf16* __restrict__ BT,
    const float* __restrict__ bias, float* __restrict__ Cf, bf16* __restrict__ Cb,
    int N, int Kd, int nbx) {
  constexpr int LA = BM / 128;          // A gloads per thread per k-tile
  constexpr int LB = BN / 128;
  constexpr int LPI = LA + LB;          // loads in flight per staged tile
  constexpr int EA = BM * 32;
  constexpr int EB = BN * 32;
  constexpr int ER = EA + EB;
  constexpr int MF = BM / 32;           // per-wave row frags (2 M-waves)
  constexpr int NF = BN / 64;           // per-wave col frags (4 N-waves) == phases
  __shared__ bf16 lds[ER * 3];
  int tid = threadIdx.x;
  int lane = tid & 63, wid = tid >> 6;
  int g = lane >> 4, lr = lane & 15;
  int wm = wid >> 2, wn = wid & 3;
  int p = blockIdx.x;
  int cpx = (int)gridDim.x >> 3;        // grid % 8 == 0 always
  int vid = (p & 7) * cpx + (p >> 3);
  int m0 = (vid / nbx) * BM;
  int n0 = (vid % nbx) * BN;
  f32x4 acc[MF][NF] = {};
  int rl = tid >> 2;
  int csw = ((tid & 3) ^ ((rl >> 1) & 3)) * 8;     // swizzled 16B slot on global src
  const bf16* pa = A + (size_t)(m0 + rl) * Kd + csw;
  const bf16* pb = BT + (size_t)(n0 + rl) * Kd + csw;
  int NT = Kd >> 5;
  auto stage = [&](int t, int buf) {
    int k0 = t << 5;
    bf16* base = lds + buf * ER + (wid << 9);      // wave-uniform dest
    #pragma unroll
    for (int rr = 0; rr < LA; rr++)
      gload16(pa + (size_t)(rr * 128) * Kd + k0, base + rr * 4096);
    #pragma unroll
    for (int rr = 0; rr < LB; rr++)
      gload16(pb + (size_t)(rr * 128) * Kd + k0, base + EA + rr * 4096);
  };
  stage(0, 0);
  stage(1, 1);
  for (int kt = 0; kt < NT; ++kt) {
    if (kt + 1 < NT) waitvm<LPI>();     // tile kt landed; tile kt+1's LPI may fly
    else             waitvm<0>();       // last tile: nothing issued after it
    barrier_raw();                      // all waves done reading tile kt-1
    const bf16* ba = lds + (kt % 3) * ER;
    const bf16* bb = ba + EA;
    if (kt + 2 < NT) stage(kt + 2, (kt + 2) % 3);  // overwrites buf freed above
    b8v af[MF], bfr[NF];
    // phase 0: read all A frags + B0,B1
    #pragma unroll
    for (int i = 0; i < MF; i++) {
      int ra = wm * (BM / 2) + i * 16 + lr;
      af[i] = *(const b8v*)(ba + ra * 32 + ((g * 8) ^ (((ra >> 1) & 3) << 3)));
    }
    #pragma unroll
    for (int j0 = 0; j0 < 2; j0++) {
      int rb = wn * (BN / 4) + j0 * 16 + lr;
      bfr[j0] = *(const b8v*)(bb + rb * 32 + ((g * 8) ^ (((rb >> 1) & 3) << 3)));
    }
    waitlgkm<0>();
    __builtin_amdgcn_sched_barrier(0);
    __builtin_amdgcn_s_setprio(1);
    #pragma unroll
    for (int i = 0; i < MF; i++) acc[i][0] = mfma16(af[i], bfr[0], acc[i][0]);
    __builtin_amdgcn_s_setprio(0);
    // phases 1..NF-1: prefetch B[j+1], counted lgkm wait, MFMA column j
    #pragma unroll
    for (int j = 1; j < NF; j++) {
      if (j + 1 < NF) {
        int rb = wn * (BN / 4) + (j + 1) * 16 + lr;
        bfr[j + 1] = *(const b8v*)(bb + rb * 32 + ((g * 8) ^ (((rb >> 1) & 3) << 3)));
        waitlgkm<1>();                  // B[j] done; B[j+1] still in flight
      } else {
        waitlgkm<0>();
      }
      __builtin_amdgcn_sched_barrier(0);
      __builtin_amdgcn_s_setprio(1);
      #pragma unroll
      for (int i = 0; i < MF; i++) acc[i][j] = mfma16(af[i], bfr[j], acc[i][j]);
      __builtin_amdgcn_s_setprio(0);
    }
  }
  #pragma unroll
  for (int i = 0; i < MF; i++) {
    #pragma unroll
    for (int j = 0; j < NF; j++) {
      int col = n0 + wn * (BN / 4) + j * 16 + lr;
      float bv = (EPI != 0) ? bias[col] : 0.0f;
      #pragma unroll
      for (int r = 0; r < 4; r++) {
        int row = m0 + wm * (BM / 2) + i * 16 + g * 4 + r;
        float v = acc[i][j][r] + bv;
        if (EPI == 0) {
          Cb[(size_t)row * N + col] = (bf16)v;
        } else if (EPI == 2) {
          Cf[(size_t)row * N + col] += v;
        } else if (EPI == 3) {
          // tanh-form gelu via hw exp: x*sigmoid(1.59577*(x+0.044715 x^3))
          float u = 1.5957691216057308f * (v + 0.044715f * v * v * v);
          float ge = v / (1.0f + __expf(-u));
          Cb[(size_t)row * N + col] = (bf16)ge;
        }
      }
    }
  }
}

// ---------------- small-GEMM kernel (token embed EPI5, output EPI4) ----------------
template<int EPI>
__global__ __launch_bounds__(256) void gemm_kernel(
    const bf16* __restrict__ A, const bf16* __restrict__ BT,
    const float* __restrict__ bias, float* __restrict__ Cf, bf16* __restrict__ Cb,
    int N, int Kd, int nbx,
    const float* __restrict__ q1, const float* __restrict__ q2, const float* __restrict__ q3,
    const float* __restrict__ alphap) {
  __shared__ bf16 As[2][4096];
  __shared__ bf16 Bs[2][4096];
  int tid = threadIdx.x;
  int lane = tid & 63, wid = tid >> 6;
  int g = lane >> 4, lr = lane & 15;
  int wm = wid >> 1, wn = wid & 1;
  int p = blockIdx.x;
  int cpx = (int)gridDim.x >> 3;
  int vid = (p & 7) * cpx + (p >> 3);
  int m0 = (vid / nbx) * 128;
  int n0 = (vid % nbx) * 128;
  f32x4 acc[4][4] = {};
  int srow = wid * 16 + (lane >> 2);
  int scol = (lane & 3) * 8;
  const bf16* pa = A + (size_t)(m0 + srow) * Kd + scol;
  const bf16* pb = BT + (size_t)(n0 + srow) * Kd + scol;
  const size_t rstep = (size_t)64 * Kd;
  int nt = Kd >> 5;
  auto stage = [&](int buf, int k0) {
    bf16* lA = &As[buf][wid * 512];
    bf16* lB = &Bs[buf][wid * 512];
    gload16(pa + k0, lA);
    gload16(pa + rstep + k0, lA + 2048);
    gload16(pb + k0, lB);
    gload16(pb + rstep + k0, lB + 2048);
  };
  stage(0, 0);
  __syncthreads();
  int cur = 0;
  for (int t = 0; t < nt; ++t) {
    if (t + 1 < nt) stage(cur ^ 1, (t + 1) * 32);
    b8v af[4], bfv[4];
    #pragma unroll
    for (int i = 0; i < 4; i++) af[i]  = *(const b8v*)&As[cur][(wm * 64 + i * 16 + lr) * 32 + g * 8];
    #pragma unroll
    for (int i = 0; i < 4; i++) bfv[i] = *(const b8v*)&Bs[cur][(wn * 64 + i * 16 + lr) * 32 + g * 8];
    #pragma unroll
    for (int mf = 0; mf < 4; mf++)
      #pragma unroll
      for (int nf = 0; nf < 4; nf++)
        acc[mf][nf] = mfma16(af[mf], bfv[nf], acc[mf][nf]);
    __syncthreads();
    cur ^= 1;
  }
  if constexpr (EPI == 4) {
    __shared__ float Ts[32][130];
    float alp = alphap[0];
    int b_ = m0 >> 11, sb = m0 & 2047;
    #pragma unroll
    for (int cg = 0; cg < 4; cg++) {
      __syncthreads();
      if (wn == (cg >> 1)) {
        #pragma unroll
        for (int nfi = 0; nfi < 2; nfi++) {
          int nf = (cg & 1) * 2 + nfi;
          int cl = nfi * 16 + lr;
          float bv = bias[cg * 32 + cl];
          #pragma unroll
          for (int mf = 0; mf < 4; mf++)
            #pragma unroll
            for (int r = 0; r < 4; r++)
              Ts[cl][wm * 64 + mf * 16 + g * 4 + r] = alp * (acc[mf][nf][r] + bv);
        }
      }
      __syncthreads();
      int cl = tid >> 3, soff = (tid & 7) * 16;
      int col = cg * 32 + cl;
      float* dst = Cf + (size_t)b_ * (KDIM * S_LEN) + (size_t)col * S_LEN + sb + soff;
      #pragma unroll
      for (int q4 = 0; q4 < 4; q4++) {
        float4 v = {Ts[cl][soff + q4*4], Ts[cl][soff + q4*4 + 1], Ts[cl][soff + q4*4 + 2], Ts[cl][soff + q4*4 + 3]};
        *(float4*)(dst + q4 * 4) = v;
      }
    }
    return;
  }
  #pragma unroll
  for (int mf = 0; mf < 4; mf++) {
    #pragma unroll
    for (int nf = 0; nf < 4; nf++) {
      int col = n0 + wn * 64 + nf * 16 + lr;
      float bv = bias[col];
      #pragma unroll
      for (int r = 0; r < 4; r++) {
        int row = m0 + wm * 64 + mf * 16 + g * 4 + r;
        float v = acc[mf][nf][r] + bv;
        if (EPI == 5) {
          int b_ = row >> 11, s_ = row & 2047;
          float pv = q1[(s_ >> 7) * 512 + col] + q2[(s_ & 127) * 512 + col] + q3[b_ * 512 + col];
          Cf[(size_t)row * N + col] = v + pv;
        }
      }
    }
  }
}

// ---------------- local windowed attention (heads 0..3) ----------------
__global__ __launch_bounds__(256) void locattn_kernel(
    const bf16* __restrict__ qkv, bf16* __restrict__ ab) {
  __shared__ bf16 Ks[128][72];        // [key][feat]
  __shared__ bf16 Vt[64][136];        // [feat][key]
  __shared__ bf16 Ps[4][32][136];     // per-wave P
  int w = blockIdx.x;
  int b = blockIdx.y >> 2, hh = blockIdx.y & 3;
  int tid = threadIdx.x, wid = tid >> 6, lane = tid & 63;
  int g = lane >> 4, lr = lane & 15;
  const size_t rowb = (size_t)b * S_LEN * QKVS;
  int qrow0 = w * WIN + wid * 32;
  b8v qf[2][2];
  #pragma unroll
  for (int mf = 0; mf < 2; mf++)
    #pragma unroll
    for (int kf = 0; kf < 2; kf++)
      qf[mf][kf] = *(const b8v*)(qkv + rowb + (size_t)(qrow0 + mf * 16 + lr) * QKVS + hh * 64 + kf * 32 + g * 8);
  float mrun[2][4], lrun[2][4];
  f32x4 oacc[2][4] = {};
  #pragma unroll
  for (int mf = 0; mf < 2; mf++)
    #pragma unroll
    for (int r = 0; r < 4; r++) { mrun[mf][r] = -3e38f; lrun[mf][r] = 0.f; }
  for (int c = 0; c < 3; c++) {
    int wc = w - 1 + c;
    if (wc < 0 || wc >= NWIN) continue;
    __syncthreads();
    {
      int row = tid >> 1, f0 = (tid & 1) * 32;
      const bf16* kp = qkv + rowb + (size_t)(wc * WIN + row) * QKVS + 512 + hh * 64 + f0;
      #pragma unroll
      for (int i = 0; i < 4; i++)
        *(b8v*)&Ks[row][f0 + i * 8] = *(const b8v*)(kp + i * 8);
      const bf16* vp = qkv + rowb + (size_t)(wc * WIN + row) * QKVS + 1024 + hh * 64 + f0;
      #pragma unroll
      for (int i = 0; i < 4; i++) {
        b8v vv = *(const b8v*)(vp + i * 8);
        #pragma unroll
        for (int j = 0; j < 8; j++) Vt[f0 + i * 8 + j][row] = vv[j];
      }
    }
    __syncthreads();
    f32x4 sc[2][8] = {};
    #pragma unroll
    for (int nf = 0; nf < 8; nf++) {
      #pragma unroll
      for (int kf = 0; kf < 2; kf++) {
        b8v kfr = *(const b8v*)&Ks[nf * 16 + lr][kf * 32 + g * 8];
        sc[0][nf] = mfma16(qf[0][kf], kfr, sc[0][nf]);
        sc[1][nf] = mfma16(qf[1][kf], kfr, sc[1][nf]);
      }
    }
    #pragma unroll
    for (int mf = 0; mf < 2; mf++) {
      #pragma unroll
      for (int r = 0; r < 4; r++) {
        float cm = -3e38f;
        #pragma unroll
        for (int nf = 0; nf < 8; nf++) { sc[mf][nf][r] *= 0.125f; cm = fmaxf(cm, sc[mf][nf][r]); }
        cm = fmaxf(cm, __shfl_xor(cm, 1));
        cm = fmaxf(cm, __shfl_xor(cm, 2));
        cm = fmaxf(cm, __shfl_xor(cm, 4));
        cm = fmaxf(cm, __shfl_xor(cm, 8));
        float mnew = fmaxf(mrun[mf][r], cm);
        float corr = __expf(mrun[mf][r] - mnew);
        float rs = 0.f;
        #pragma unroll
        for (int nf = 0; nf < 8; nf++) { float p = __expf(sc[mf][nf][r] - mnew); sc[mf][nf][r] = p; rs += p; }
        rs += __shfl_xor(rs, 1); rs += __shfl_xor(rs, 2);
        rs += __shfl_xor(rs, 4); rs += __shfl_xor(rs, 8);
        lrun[mf][r] = lrun[mf][r] * corr + rs;
        mrun[mf][r] = mnew;
        #pragma unroll
        for (int vf = 0; vf < 4; vf++) oacc[mf][vf][r] *= corr;
      }
    }
    #pragma unroll
    for (int mf = 0; mf < 2; mf++)
      #pragma unroll
      for (int nf = 0; nf < 8; nf++)
        #pragma unroll
        for (int r = 0; r < 4; r++)
          Ps[wid][mf * 16 + g * 4 + r][nf * 16 + lr] = (bf16)sc[mf][nf][r];
    #pragma unroll
    for (int kf2 = 0; kf2 < 4; kf2++) {
      b8v pa0 = *(const b8v*)&Ps[wid][lr][kf2 * 32 + g * 8];
      b8v pa1 = *(const b8v*)&Ps[wid][16 + lr][kf2 * 32 + g * 8];
      #pragma unroll
      for (int vf = 0; vf < 4; vf++) {
        b8v vv = *(const b8v*)&Vt[vf * 16 + lr][kf2 * 32 + g * 8];
        oacc[0][vf] = mfma16(pa0, vv, oacc[0][vf]);
        oacc[1][vf] = mfma16(pa1, vv, oacc[1][vf]);
      }
    }
  }
  #pragma unroll
  for (int mf = 0; mf < 2; mf++) {
    #pragma unroll
    for (int r = 0; r < 4; r++) {
      float inv = 1.0f / lrun[mf][r];
      int row = qrow0 + mf * 16 + g * 4 + r;
      #pragma unroll
      for (int vf = 0; vf < 4; vf++)
        ab[(size_t)b * S_LEN * DMODEL + (size_t)row * DMODEL + hh * 64 + vf * 16 + lr] = (bf16)(oacc[mf][vf][r] * inv);
    }
  }
}

// ---------------- linear attention (heads 4..7), no-max exp ----------------

__global__ __launch_bounds__(256) void la2_kernel(const bf16* __restrict__ qkv,
    float* __restrict__ part, float* __restrict__ psum) {
  int ch = blockIdx.x, bh = blockIdx.y;
  int b = bh >> 2, hh = bh & 3;
  __shared__ float ke[128][65];
  __shared__ float vsh[128][65];
  __shared__ float red[4][64];
  int tid = threadIdx.x;
  const float scale = 0.35355339059327373f;
  const size_t base = ((size_t)b * S_LEN + (size_t)ch * 128) * QKVS;
  const bf16* kp = qkv + base + 768 + hh * 64;
  const bf16* vp = qkv + base + 1280 + hh * 64;
  for (int i = tid; i < 1024; i += 256) {
    int s = i >> 3, d0 = (i & 7) * 8;
    b8v kv = *(const b8v*)(kp + (size_t)s * QKVS + d0);
    b8v vv = *(const b8v*)(vp + (size_t)s * QKVS + d0);
    #pragma unroll
    for (int j = 0; j < 8; j++) {
      ke[s][d0 + j] = __expf((float)kv[j] * scale);
      vsh[s][d0 + j] = (float)vv[j];
    }
  }
  __syncthreads();
  int d = tid & 63, sg = tid >> 6;
  float ps = 0.f;
  for (int s = sg * 32; s < sg * 32 + 32; s++) ps += ke[s][d];
  red[sg][d] = ps;
  int e = tid & 63, dg = tid >> 6;
  float accv[16] = {};
  for (int s = 0; s < 128; s++) {
    float vv2 = vsh[s][e];
    #pragma unroll
    for (int i = 0; i < 16; i++) accv[i] = fmaf(ke[s][dg * 16 + i], vv2, accv[i]);
  }
  __syncthreads();
  float* pp = part + ((size_t)ch * 32 + bh) * 4096 + (size_t)dg * 16 * 64 + e;
  #pragma unroll
  for (int i = 0; i < 16; i++) pp[i * 64] = accv[i];
  if (tid < 64)
    psum[((size_t)ch * 32 + bh) * 64 + tid] = red[0][tid] + red[1][tid] + red[2][tid] + red[3][tid];
}

__global__ __launch_bounds__(256) void la2b_kernel(const float* __restrict__ part,
    const float* __restrict__ psum, float* __restrict__ ctx) {
  int idx = blockIdx.x * 256 + threadIdx.x;    // 131072 total
  int bh = idx >> 12;
  int d = (idx >> 6) & 63;
  float s = 0.f, cs = 0.f;
  for (int c = 0; c < 16; c++) {
    s += part[(size_t)c * 131072 + idx];
    cs += psum[(size_t)(c * 32 + bh) * 64 + d];
  }
  ctx[idx] = s / cs;
}

__global__ __launch_bounds__(256) void la3_kernel(const bf16* __restrict__ qkv,
    const float* __restrict__ ctx, bf16* __restrict__ ab) {
  int ch = blockIdx.x, bh = blockIdx.y;
  int b = bh >> 2, hh = bh & 3;
  __shared__ float cs[64][65];
  int tid = threadIdx.x;
  for (int i = tid; i < 4096; i += 256) cs[i >> 6][i & 63] = ctx[(size_t)bh * 4096 + i];
  __syncthreads();
  int s = ch * 128 + (tid >> 1);
  int e0 = (tid & 1) * 32;
  const float scale = 0.35355339059327373f;
  const bf16* qr = qkv + ((size_t)b * S_LEN + s) * QKVS + 256 + hh * 64;
  float qv[64];
  float mx = -3e38f;
  #pragma unroll
  for (int i = 0; i < 8; i++) {
    b8v qq = *(const b8v*)(qr + i * 8);
    #pragma unroll
    for (int j = 0; j < 8; j++) { qv[i * 8 + j] = (float)qq[j] * scale; mx = fmaxf(mx, qv[i * 8 + j]); }
  }
  float sum = 0.f;
  #pragma unroll
  for (int dd = 0; dd < 64; dd++) { qv[dd] = __expf(qv[dd] - mx); sum += qv[dd]; }
  float inv = 1.f / sum;
  float o[32] = {};
  #pragma unroll
  for (int dd = 0; dd < 64; dd++) {
    float qq = qv[dd] * inv;
    #pragma unroll
    for (int j = 0; j < 32; j++) o[j] = fmaf(qq, cs[dd][e0 + j], o[j]);
  }
  bf16* op = ab + ((size_t)b * S_LEN + s) * DMODEL + 256 + hh * 64 + e0;
  #pragma unroll
  for (int j = 0; j < 32; j++) op[j] = (bf16)o[j];
}

// ---------------- launcher ----------------

extern "C" void kernel_launch(void* const* d_in, const int* in_sizes, int n_in,
                              void* d_out, int out_size, void* d_ws, size_t ws_size,
                              hipStream_t stream) {
  (void)in_sizes; (void)n_in; (void)out_size; (void)ws_size;
  const float* x_f     = (const float*)d_in[0];
  const int*   t_i     = (const int*)  d_in[1];
  const float* token_w = (const float*)d_in[2];
  const float* token_b = (const float*)d_in[3];
  const float* ax1     = (const float*)d_in[4];
  const float* ax2     = (const float*)d_in[5];
  const float* time_w1 = (const float*)d_in[6];
  const float* time_b1 = (const float*)d_in[7];
  const float* time_w2 = (const float*)d_in[8];
  const float* time_b2 = (const float*)d_in[9];
  const float* ln1_g   = (const float*)d_in[10];
  const float* ln1_b   = (const float*)d_in[11];
  const float* wq      = (const float*)d_in[12];
  const float* wk      = (const float*)d_in[13];
  const float* wv      = (const float*)d_in[14];
  const float* wo      = (const float*)d_in[15];
  const float* wo_b    = (const float*)d_in[16];
  const float* ln2_g   = (const float*)d_in[17];
  const float* ln2_b   = (const float*)d_in[18];
  const float* ff_w1   = (const float*)d_in[19];
  const float* ff_b1   = (const float*)d_in[20];
  const float* ff_w2   = (const float*)d_in[21];
  const float* ff_b2   = (const float*)d_in[22];
  const float* norm_g  = (const float*)d_in[23];
  const float* norm_b  = (const float*)d_in[24];
  const float* out_w   = (const float*)d_in[25];
  const float* out_b   = (const float*)d_in[26];
  const float* alpha   = (const float*)d_in[27];

  char* ws = (char*)d_ws;
  float* h      = (float*)(ws + 0);            // 33,554,432
  float* te1    = (float*)(ws + 33554432);     // 65,536
  float* te2    = (float*)(ws + 33619968);     // 16,384
  float* psum   = (float*)(ws + 33636352);     // 131,072
  float* ctx    = (float*)(ws + 33767424);     // 524,288
  float* part   = (float*)(ws + 34291712);     // 8,388,608
  bf16* nbuf    = (bf16*)(ws + 42680320);      // 16,777,216
  bf16* qkvb    = (bf16*)(ws + 59457536);      // 50,331,648
  bf16* abuf    = (bf16*)(ws + 109789184);     // 16,777,216
  bf16* gbuf    = qkvb;                        // ff1 out aliases qkv+abuf (dead by then)
  bf16* xw      = (bf16*)(ws + 126566400);     // 4,194,304
  bf16* token_wT= (bf16*)(ws + 130760704);     // 131,072
  bf16* wqkvT   = (bf16*)(ws + 130891776);     // 6,291,456  [L][1536][512]
  bf16* woT     = (bf16*)(ws + 137183232);     // 2,097,152
  bf16* ff1T    = (bf16*)(ws + 139280384);     // 8,388,608
  bf16* ff2T    = (bf16*)(ws + 147668992);     // 8,388,608
  bf16* outwT   = (bf16*)(ws + 156057600);     // 131,072

  conv_kernel<<<2048, 256, 0, stream>>>(x_f, xw, 2097152);
  convT_kernel<<<dim3(4, 16, 1),  256, 0, stream>>>(token_w, token_wT, 128, 512, 65536, 65536);
  convT_kernel<<<dim3(16, 16, 4), 256, 0, stream>>>(wq, wqkvT,           512, 512, 262144, 786432);
  convT_kernel<<<dim3(16, 16, 4), 256, 0, stream>>>(wk, wqkvT + 262144,  512, 512, 262144, 786432);
  convT_kernel<<<dim3(16, 16, 4), 256, 0, stream>>>(wv, wqkvT + 524288,  512, 512, 262144, 786432);
  convT_kernel<<<dim3(16, 16, 4), 256, 0, stream>>>(wo, woT, 512, 512, 262144, 262144);
  convT_kernel<<<dim3(16, 64, 4), 256, 0, stream>>>(ff_w1, ff1T, 512, 2048, 1048576, 1048576);
  convT_kernel<<<dim3(64, 16, 4), 256, 0, stream>>>(ff_w2, ff2T, 2048, 512, 1048576, 1048576);
  convT_kernel<<<dim3(16, 4, 1),  256, 0, stream>>>(out_w, outwT, 512, 128, 65536, 65536);

  time1_kernel<<<256, 256, 0, stream>>>(t_i, time_w1, time_b1, te1);
  time2_kernel<<<64, 256, 0, stream>>>(te1, time_w2, time_b2, te2);

  // token embedding + pos/time add fused
  gemm_kernel<5><<<512, 256, 0, stream>>>(xw, token_wT, token_b, h, nullptr, 512, 128, 4, ax1, ax2, te2, nullptr);

  for (int l = 0; l < 4; l++) {
    ln_kernel<<<4096, 256, 0, stream>>>(h, ln1_g + l * 512, ln1_b + l * 512, nbuf);
    gemm3_kernel<0, 128, 256><<<768, 512, 0, stream>>>(nbuf, wqkvT + (size_t)l * 786432, nullptr, nullptr, qkvb, 1536, 512, 6);
    locattn_kernel<<<dim3(16, 32), 256, 0, stream>>>(qkvb, abuf);
    la2_kernel<<<dim3(16, 32), 256, 0, stream>>>(qkvb, part, psum);
    la2b_kernel<<<512, 256, 0, stream>>>(part, psum, ctx);
    la3_kernel<<<dim3(16, 32), 256, 0, stream>>>(qkvb, ctx, abuf);
    gemm3_kernel<2, 128, 256><<<256, 512, 0, stream>>>(abuf, woT + (size_t)l * 262144, wo_b + l * 512, h, nullptr, 512, 512, 2);
    ln_kernel<<<4096, 256, 0, stream>>>(h, ln2_g + l * 512, ln2_b + l * 512, nbuf);
    gemm3_kernel<3, 256, 256><<<512, 512, 0, stream>>>(nbuf, ff1T + (size_t)l * 1048576, ff_b1 + l * 2048, nullptr, gbuf, 2048, 512, 8);
    gemm3_kernel<2, 128, 256><<<256, 512, 0, stream>>>(gbuf, ff2T + (size_t)l * 1048576, ff_b2 + l * 512, h, nullptr, 512, 2048, 2);
  }

  ln_kernel<<<4096, 256, 0, stream>>>(h, norm_g, norm_b, nbuf);
  gemm_kernel<4><<<128, 256, 0, stream>>>(nbuf, outwT, out_b, (float*)d_out, nullptr, 128, 512, 1, nullptr, nullptr, nullptr, alpha);
}